// Round 6
// baseline (384.442 us; speedup 1.0000x reference)
//
#include <hip/hip_runtime.h>
#include <math.h>

#define NB 8
#define NC 128
#define NPOS 2000
#define NK 32000
#define IN_EPS 1e-3f
#define BN_EPS 1e-5f

typedef short bf16x8 __attribute__((ext_vector_type(8)));
typedef _Float16 f16x8 __attribute__((ext_vector_type(8)));
typedef float f32x4 __attribute__((ext_vector_type(4)));
typedef unsigned short ushort_t;
typedef unsigned int uint_t;

// LDS row stride in ushorts (128 payload + 8 pad; keeps 16B alignment, 272B rows)
#define XSTRIDE 136

// ---- workspace layout ----
// [0 .. 32768)      sumP  : 32 buckets x (8b x 128c), bucket-major   (floats)
// [32768 .. 65536)  sqP
// [65536 .. 66560)  alpha
// [66560 .. 67584)  beta
// byte 270336:      weights w0,wq,wk,wv (16384 ushorts each; f16 on v2 path)
// byte 401408:      h buffer: [b][pos][136] fp16 (padded rows, 272B each)
#define WSF_SUMP  0
#define WSF_SQP   32768
#define WSF_ALPHA 65536
#define WSF_BETA  66560
#define WSB_WEIGHTS 270336
#define WSB_H     401408
#define WS_NEEDED ((size_t)WSB_H + (size_t)NB * NK * XSTRIDE * 2)

__device__ __forceinline__ f32x4 mfma_bf16(bf16x8 a, bf16x8 b, f32x4 c) {
  return __builtin_amdgcn_mfma_f32_16x16x32_bf16(a, b, c, 0, 0, 0);
}
__device__ __forceinline__ f32x4 mfma_f16(f16x8 a, f16x8 b, f32x4 c) {
  return __builtin_amdgcn_mfma_f32_16x16x32_f16(a, b, c, 0, 0, 0);
}

// fp32 -> bf16 round-to-nearest-even
__device__ __forceinline__ ushort_t f2bf(float f) {
  unsigned u = __float_as_uint(f);
  return (ushort_t)((u + 0x7FFFu + ((u >> 16) & 1u)) >> 16);
}
__device__ __forceinline__ ushort_t f2h(float f) {
  union { _Float16 h; ushort_t u; } cv;
  cv.h = (_Float16)f;
  return cv.u;
}
__device__ __forceinline__ float h2f(ushort_t u) {
  union { _Float16 h; ushort_t u; } cv;
  cv.u = u;
  return (float)cv.h;
}
// packed fp32x2 -> fp16x2 (round-toward-zero), single VALU op.
// NOTE: builtin returns __fp16 ext_vector(2); capture with auto + bit_cast.
__device__ __forceinline__ uint_t pk2h(float a, float b) {
  auto h = __builtin_amdgcn_cvt_pkrtz(a, b);
  return __builtin_bit_cast(uint_t, h);
}

// ---------------- K0: cast weights (ALL_F16: every matrix -> fp16; else bf16) ----------------
template <int ALL_F16>
__global__ __launch_bounds__(256) void k_prep(const float* __restrict__ w0,
    const float* __restrict__ wq, const float* __restrict__ wk,
    const float* __restrict__ wv, ushort_t* __restrict__ wb) {
  int idx = blockIdx.x * 256 + threadIdx.x;  // 0..65535
  int m = idx >> 14;
  int e = idx & 16383;
  const float* src = (m == 0) ? w0 : (m == 1) ? wq : (m == 2) ? wk : wv;
  float v = src[e];
  wb[m * 16384 + e] = ALL_F16 ? f2h(v) : f2bf(v);
}

// ---- staging (v1 fallback): Xt[col][cin] bf16, 128 columns ----
__device__ __forceinline__ void stage_xt128(const float* __restrict__ xb,
                                            ushort_t* __restrict__ xt, int tid) {
  const int col = tid & 127;
  const int hi = tid >> 7;  // 0/1
  const float* p = xb + col;
#pragma unroll
  for (int i = 0; i < 8; ++i) {
    const int c0 = hi * 64 + i * 8;
    ushort_t u[8] __attribute__((aligned(16)));
#pragma unroll
    for (int j = 0; j < 8; ++j) u[j] = f2bf(p[(size_t)(c0 + j) * NK]);
    *(uint4*)(xt + col * XSTRIDE + c0) = *(const uint4*)u;
  }
}

// ---- staging (v1 fallback): 64 columns, bf16 ----
__device__ __forceinline__ void stage_xt64(const float* __restrict__ xb,
                                           ushort_t* __restrict__ xt, int tid) {
  const int col = tid & 63;
  const int hi = tid >> 6;  // 0..3
  const float* p = xb + col;
#pragma unroll
  for (int i = 0; i < 4; ++i) {
    const int c0 = hi * 32 + i * 8;
    ushort_t u[8] __attribute__((aligned(16)));
#pragma unroll
    for (int j = 0; j < 8; ++j) u[j] = f2bf(p[(size_t)(c0 + j) * NK]);
    *(uint4*)(xt + col * XSTRIDE + c0) = *(const uint4*)u;
  }
}

// ---- staging v4: 64 columns, fp16 via v_cvt_pkrtz; 16 loads in flight per batch ----
__device__ __forceinline__ void stage_xt64_f16(const float* __restrict__ xb,
                                               ushort_t* __restrict__ xt, int tid) {
  const int col = tid & 63;
  const int hi = tid >> 6;  // 0..3 -> 32 channels each
  const float* p = xb + col;
#pragma unroll
  for (int r = 0; r < 2; ++r) {
    const int c0 = hi * 32 + r * 16;
    float v[16];
#pragma unroll
    for (int j = 0; j < 16; ++j) v[j] = p[(size_t)(c0 + j) * NK];
    uint_t u[8] __attribute__((aligned(16)));
#pragma unroll
    for (int j = 0; j < 8; ++j) u[j] = pk2h(v[2 * j], v[2 * j + 1]);
    *(uint4*)(xt + col * XSTRIDE + c0) = *(const uint4*)u;
    *(uint4*)(xt + col * XSTRIDE + c0 + 8) = *(const uint4*)(u + 4);
  }
}

// ---------------- K1 v4: conv (f16) + stats + materialize h (fp16, padded rows) ----------------
// 64-pos tile, 18.4KB LDS. Conv output kept in 16 regs (static idx); after the
// post-MFMA barrier the dead xt tile stages h so the global h-store is ONE
// contiguous 17,408B coalesced copy (full-line writes, no RFO).
// Stats computed from the fp16-ROUNDED h (keeps the BN-mean==0 identity in k_fold).
__global__ __launch_bounds__(256, 6) void k_stats2(const float* __restrict__ x,
    const ushort_t* __restrict__ w0b, float* __restrict__ sumP,
    float* __restrict__ sqP, ushort_t* __restrict__ hg) {
  __shared__ ushort_t xt[64 * XSTRIDE] __attribute__((aligned(16)));
  __shared__ float ssum[128], ssq[128];
  const int b = blockIdx.y;
  const int tid = threadIdx.x;
  stage_xt64_f16(x + (size_t)b * NC * NK + (size_t)blockIdx.x * 64, xt, tid);
  __syncthreads();
  const int lane = tid & 63, w = tid >> 6;
  const int m = lane & 15, quad = lane >> 4;

  uint2 hreg[8];  // [p*4+t], statically indexed (fully unrolled loops)

#pragma unroll
  for (int p = 0; p < 2; ++p) {
    const int ch0 = (w + p * 4) * 16;
    f16x8 wf[4];
#pragma unroll
    for (int kb = 0; kb < 4; ++kb)
      wf[kb] = *(const f16x8*)(w0b + (ch0 + m) * 128 + kb * 32 + quad * 8);
    float s0 = 0.f, s1 = 0.f, s2 = 0.f, s3 = 0.f;
    float q0 = 0.f, q1 = 0.f, q2 = 0.f, q3 = 0.f;
#pragma unroll
    for (int t = 0; t < 4; ++t) {
      const ushort_t* xr = xt + (t * 16 + m) * XSTRIDE;
      f32x4 acc = {0.f, 0.f, 0.f, 0.f};
#pragma unroll
      for (int kb = 0; kb < 4; ++kb) {
        f16x8 bx = *(const f16x8*)(xr + kb * 32 + quad * 8);
        acc = mfma_f16(wf[kb], bx, acc);
      }
      const ushort_t u0 = f2h(acc[0]), u1 = f2h(acc[1]);
      const ushort_t u2 = f2h(acc[2]), u3 = f2h(acc[3]);
      uint2 pk;
      pk.x = (uint_t)u0 | ((uint_t)u1 << 16);
      pk.y = (uint_t)u2 | ((uint_t)u3 << 16);
      hreg[p * 4 + t] = pk;
      const float r0 = h2f(u0), r1 = h2f(u1), r2 = h2f(u2), r3 = h2f(u3);
      s0 += r0; s1 += r1; s2 += r2; s3 += r3;
      q0 = fmaf(r0, r0, q0); q1 = fmaf(r1, r1, q1);
      q2 = fmaf(r2, r2, q2); q3 = fmaf(r3, r3, q3);
    }
    // positions live across the 16 m-lanes: butterfly over lane bits 0..3
#pragma unroll
    for (int d = 1; d < 16; d <<= 1) {
      s0 += __shfl_xor(s0, d); s1 += __shfl_xor(s1, d);
      s2 += __shfl_xor(s2, d); s3 += __shfl_xor(s3, d);
      q0 += __shfl_xor(q0, d); q1 += __shfl_xor(q1, d);
      q2 += __shfl_xor(q2, d); q3 += __shfl_xor(q3, d);
    }
    if (m == 0) {  // strips disjoint across (w,p,quad) -> plain stores
      ssum[ch0 + quad * 4 + 0] = s0; ssum[ch0 + quad * 4 + 1] = s1;
      ssum[ch0 + quad * 4 + 2] = s2; ssum[ch0 + quad * 4 + 3] = s3;
      ssq[ch0 + quad * 4 + 0] = q0; ssq[ch0 + quad * 4 + 1] = q1;
      ssq[ch0 + quad * 4 + 2] = q2; ssq[ch0 + quad * 4 + 3] = q3;
    }
  }
  __syncthreads();  // all xt reads done; ssum/ssq visible

  // phase C: scatter h fragments into the dead xt tile (LDS, cheap)
#pragma unroll
  for (int p = 0; p < 2; ++p) {
    const int ch0 = (w + p * 4) * 16;
#pragma unroll
    for (int t = 0; t < 4; ++t)
      *(uint2*)(xt + (t * 16 + m) * XSTRIDE + ch0 + quad * 4) = hreg[p * 4 + t];
  }
  __syncthreads();

  // phase D: one contiguous coalesced 17,408B store LDS -> global
  {
    const uint4* src = (const uint4*)xt;
    uint4* dst =
        (uint4*)(hg + ((size_t)b * NK + (size_t)blockIdx.x * 64) * XSTRIDE);
#pragma unroll
    for (int i = 0; i < 4; ++i) dst[i * 256 + tid] = src[i * 256 + tid];
    if (tid < 64) dst[1024 + tid] = src[1024 + tid];
  }

  if (tid < 128) {
    const int bucket = blockIdx.x & 31;
    atomicAdd(&sumP[bucket * 1024 + b * 128 + tid], ssum[tid]);
    atomicAdd(&sqP[bucket * 1024 + b * 128 + tid], ssq[tid]);
  }
}

// ---------------- K2: reduce buckets, fold IN+BN into per-(b,c) alpha/beta ----------------
__global__ void k_fold(const float* __restrict__ ws_in, const float* __restrict__ bn_g,
                       const float* __restrict__ bn_b, float* __restrict__ alpha,
                       float* __restrict__ beta) {
  int c = threadIdx.x;  // 128 threads
  const float* sumP = ws_in + WSF_SUMP;
  const float* sqP = ws_in + WSF_SQP;
  float var[NB], muv[NB];
  float bvar = 0.f;
#pragma unroll 1
  for (int b = 0; b < NB; ++b) {
    float s = 0.f, q = 0.f;
#pragma unroll
    for (int k = 0; k < 32; ++k) {
      s += sumP[k * 1024 + b * 128 + c];
      q += sqP[k * 1024 + b * 128 + c];
    }
    float mu = s * (1.f / NK);
    float v = q * (1.f / NK) - mu * mu;
    muv[b] = mu;
    var[b] = v;
    bvar += v / (v + IN_EPS);
  }
  bvar *= 0.125f;
  float s2 = rsqrtf(bvar + BN_EPS);
  float g = bn_g[c], bb = bn_b[c];
#pragma unroll
  for (int b = 0; b < NB; ++b) {
    float a = rsqrtf(var[b] + IN_EPS) * s2 * g;
    alpha[b * 128 + c] = a;
    beta[b * 128 + c] = bb - muv[b] * a;
  }
}

// normalize 2 packed fp16 with per-channel alpha/beta + relu, repack (1 cvt op out)
__device__ __forceinline__ uint_t norm2(uint_t hv, float a0, float a1, float c0,
                                        float c1) {
  float lo = h2f((ushort_t)(hv & 0xffffu));
  float hi = h2f((ushort_t)(hv >> 16));
  return pk2h(fmaxf(fmaf(lo, a0, c0), 0.f), fmaxf(fmaf(hi, a1, c1), 0.f));
}

// ---------------- K3 v5: load h (+norm fused in staging) -> qkv+softmax+agg ----------------
// launch_bounds(256,8): VGPR measured 52 (fits 64-reg budget); LDS 19,968B x 8 =
// 159,744 <= 160KB -> 8 blocks/CU. Empirical: the 2nd launch_bounds arg tracks
// achieved occupancy on this stack ((256,4)->35%, (256,8)->77%); this kernel is
// latency-bound (all pipes <26%), so occupancy is the lever.
__global__ __launch_bounds__(256, 8) void k_fused2(
    const ushort_t* __restrict__ hg, const float* __restrict__ x_row,
    const ushort_t* __restrict__ wb, const float* __restrict__ alpha,
    const float* __restrict__ beta, const float* __restrict__ bq,
    const float* __restrict__ bk, const float* __restrict__ bv,
    const float* __restrict__ g1p, float* __restrict__ out) {
  __shared__ ushort_t xt[64 * XSTRIDE] __attribute__((aligned(16)));  // 17408 B
  __shared__ float souts[128 * 5];                                    // 2560 B
  const int b = blockIdx.y;
  const int tid = threadIdx.x;
  const int lane = tid & 63, w = tid >> 6;

  // hoist epilogue x_row load (independent; hides HBM latency under QKV)
  const size_t oi = ((size_t)b * NC + tid) * NPOS + blockIdx.x * 4;
  float4 xr_early;
  if (tid < 128) xr_early = *(const float4*)(x_row + oi);

  // stage + fused norm: 1088 uint4 chunks (17,408 B). Row = j/17; chunk c=j%17
  // covers channels c*8..c*8+7 (c==16 is the 16B pad -> raw copy).
  {
    const uint4* src =
        (const uint4*)(hg + ((size_t)b * NK + (size_t)blockIdx.x * 64) * XSTRIDE);
    uint4* dst = (uint4*)xt;
    const float* ap = alpha + b * 128;
    const float* bp = beta + b * 128;
#pragma unroll
    for (int i = 0; i < 5; ++i) {
      if (i < 4 || tid < 64) {
        const int j = i * 256 + tid;
        uint4 v = src[j];
        const int c = j % 17;
        if (c < 16) {
          const int ch = c * 8;
          const float4 a0 = *(const float4*)(ap + ch);
          const float4 a1 = *(const float4*)(ap + ch + 4);
          const float4 c0 = *(const float4*)(bp + ch);
          const float4 c1 = *(const float4*)(bp + ch + 4);
          v.x = norm2(v.x, a0.x, a0.y, c0.x, c0.y);
          v.y = norm2(v.y, a0.z, a0.w, c0.z, c0.w);
          v.z = norm2(v.z, a1.x, a1.y, c1.x, c1.y);
          v.w = norm2(v.w, a1.z, a1.w, c1.z, c1.w);
        }
        dst[j] = v;
      }
    }
  }
  const float g1 = g1p[0];
  __syncthreads();

  // ---- QKV phase (fp16) ----
  const int m = lane & 15, quad = lane >> 4;
  const ushort_t* wqb = wb + 16384;
  const ushort_t* wkb = wb + 32768;
  const ushort_t* wvb = wb + 49152;
#pragma unroll 1
  for (int p = 0; p < 2; ++p) {
    const int ch0 = (w + p * 4) * 16;
    f16x8 wqf[4], wkf[4], wvf[4];
#pragma unroll
    for (int kb = 0; kb < 4; ++kb) {
      wqf[kb] = *(const f16x8*)(wqb + (ch0 + m) * 128 + kb * 32 + quad * 8);
      wkf[kb] = *(const f16x8*)(wkb + (ch0 + m) * 128 + kb * 32 + quad * 8);
      wvf[kb] = *(const f16x8*)(wvb + (ch0 + m) * 128 + kb * 32 + quad * 8);
    }
    const float bqv = bq[ch0 + m];
    const float bkv = bk[ch0 + m];
    const float bvv = bv[ch0 + m];
#pragma unroll 1
    for (int t = 0; t < 4; ++t) {
      const ushort_t* hr = xt + (t * 16 + m) * XSTRIDE;
      f16x8 af[4];
#pragma unroll
      for (int kb = 0; kb < 4; ++kb)
        af[kb] = *(const f16x8*)(hr + kb * 32 + quad * 8);
      f32x4 qa = {0.f, 0.f, 0.f, 0.f};
      f32x4 ka = {0.f, 0.f, 0.f, 0.f};
#pragma unroll
      for (int kb = 0; kb < 4; ++kb) qa = mfma_f16(af[kb], wqf[kb], qa);
#pragma unroll
      for (int kb = 0; kb < 4; ++kb) ka = mfma_f16(af[kb], wkf[kb], ka);
      // D: col=lane&15 -> outch-in-strip, row=quad*4+r -> neighbor
      float p0 = (qa[0] + bqv) * (ka[0] + bkv);
      float p1 = (qa[1] + bqv) * (ka[1] + bkv);
      float p2 = (qa[2] + bqv) * (ka[2] + bkv);
      float p3 = (qa[3] + bqv) * (ka[3] + bkv);
      float mx = fmaxf(fmaxf(p0, p1), fmaxf(p2, p3));
      mx = fmaxf(mx, __shfl_xor(mx, 16));
      mx = fmaxf(mx, __shfl_xor(mx, 32));
      float e0 = __expf(p0 - mx), e1 = __expf(p1 - mx);
      float e2 = __expf(p2 - mx), e3 = __expf(p3 - mx);
      float sm = (e0 + e1) + (e2 + e3);
      sm += __shfl_xor(sm, 16);
      sm += __shfl_xor(sm, 32);
      f32x4 va = {0.f, 0.f, 0.f, 0.f};
#pragma unroll
      for (int kb = 0; kb < 4; ++kb) va = mfma_f16(af[kb], wvf[kb], va);
      // sum_k e_k*(v_k+bv) = sum e_k*v_k + bv*sum e_k  ->  add bv after divide
      float r0 = e0 * va[0] + e1 * va[1] + e2 * va[2] + e3 * va[3];
      r0 += __shfl_xor(r0, 16);
      r0 += __shfl_xor(r0, 32);
      if (quad == 0) souts[(ch0 + m) * 5 + t] = r0 / sm + bvv;
    }
  }
  __syncthreads();

  // ---- coalesced epilogue: out = x_row + g1 * souts ----
  if (tid < 128) {
    const float* sp = souts + tid * 5;
    float4 o;
    o.x = xr_early.x + g1 * sp[0];
    o.y = xr_early.y + g1 * sp[1];
    o.z = xr_early.z + g1 * sp[2];
    o.w = xr_early.w + g1 * sp[3];
    *(float4*)(out + oi) = o;
  }
}

// =================== v1 fallback path (used only if workspace too small) ===================
__global__ __launch_bounds__(256, 4) void k_stats1(const float* __restrict__ x,
    const ushort_t* __restrict__ w0b, float* __restrict__ sumP,
    float* __restrict__ sqP) {
  __shared__ ushort_t xt[128 * XSTRIDE];
  __shared__ float ssum[128], ssq[128];
  const int b = blockIdx.y;
  const int tid = threadIdx.x;
  stage_xt128(x + (size_t)b * NC * NK + (size_t)blockIdx.x * 128, xt, tid);
  __syncthreads();
  const int lane = tid & 63, w = tid >> 6;
  const int m = lane & 15, quad = lane >> 4;

#pragma unroll 1
  for (int p = 0; p < 2; ++p) {
    const int ch0 = (w + p * 4) * 16;
    bf16x8 wf[4];
#pragma unroll
    for (int kb = 0; kb < 4; ++kb)
      wf[kb] = *(const bf16x8*)(w0b + (ch0 + m) * 128 + kb * 32 + quad * 8);
    float s = 0.f, q2 = 0.f;
#pragma unroll 2
    for (int t = 0; t < 8; ++t) {
      const ushort_t* xr = xt + (t * 16 + m) * XSTRIDE;
      f32x4 acc = {0.f, 0.f, 0.f, 0.f};
#pragma unroll
      for (int kb = 0; kb < 4; ++kb) {
        bf16x8 af = *(const bf16x8*)(xr + kb * 32 + quad * 8);
        acc = mfma_bf16(af, wf[kb], acc);
      }
      s += (acc[0] + acc[1]) + (acc[2] + acc[3]);
      q2 += (acc[0] * acc[0] + acc[1] * acc[1]) +
            (acc[2] * acc[2] + acc[3] * acc[3]);
    }
    s += __shfl_xor(s, 16);
    s += __shfl_xor(s, 32);
    q2 += __shfl_xor(q2, 16);
    q2 += __shfl_xor(q2, 32);
    if (quad == 0) {
      ssum[ch0 + m] = s;
      ssq[ch0 + m] = q2;
    }
  }
  __syncthreads();
  if (tid < 128) {
    const int bucket = blockIdx.x & 31;
    atomicAdd(&sumP[bucket * 1024 + b * 128 + tid], ssum[tid]);
    atomicAdd(&sqP[bucket * 1024 + b * 128 + tid], ssq[tid]);
  }
}

__global__ __launch_bounds__(256, 4) void k_fused1(const float* __restrict__ x,
    const float* __restrict__ x_row, const ushort_t* __restrict__ wb,
    const float* __restrict__ alpha, const float* __restrict__ beta,
    const float* __restrict__ bq, const float* __restrict__ bk,
    const float* __restrict__ bv, const float* __restrict__ g1p,
    float* __restrict__ out) {
  __shared__ ushort_t xt[64 * XSTRIDE];
  __shared__ ushort_t ht[64 * XSTRIDE];
  __shared__ float souts[128 * 5];
  const int b = blockIdx.y;
  const int tid = threadIdx.x;
  stage_xt64(x + (size_t)b * NC * NK + (size_t)blockIdx.x * 64, xt, tid);
  const float g1 = g1p[0];
  __syncthreads();
  const int lane = tid & 63, w = tid >> 6;
  const int m = lane & 15, quad = lane >> 4;
  const ushort_t* w0b = wb;
  const ushort_t* wqb = wb + 16384;
  const ushort_t* wkb = wb + 32768;
  const ushort_t* wvb = wb + 49152;

#pragma unroll 1
  for (int p = 0; p < 2; ++p) {
    const int ch0 = (w + p * 4) * 16;
    bf16x8 wf[4];
#pragma unroll
    for (int kb = 0; kb < 4; ++kb)
      wf[kb] = *(const bf16x8*)(w0b + (ch0 + m) * 128 + kb * 32 + quad * 8);
    const float4 av = *(const float4*)(alpha + b * 128 + ch0 + quad * 4);
    const float4 bev = *(const float4*)(beta + b * 128 + ch0 + quad * 4);
#pragma unroll
    for (int t = 0; t < 4; ++t) {
      const ushort_t* xr = xt + (t * 16 + m) * XSTRIDE;
      f32x4 acc = {0.f, 0.f, 0.f, 0.f};
#pragma unroll
      for (int kb = 0; kb < 4; ++kb) {
        bf16x8 bx = *(const bf16x8*)(xr + kb * 32 + quad * 8);
        acc = mfma_bf16(wf[kb], bx, acc);
      }
      float h0 = fmaxf(acc[0] * av.x + bev.x, 0.f);
      float h1 = fmaxf(acc[1] * av.y + bev.y, 0.f);
      float h2 = fmaxf(acc[2] * av.z + bev.z, 0.f);
      float h3 = fmaxf(acc[3] * av.w + bev.w, 0.f);
      uint2 pk;
      pk.x = (uint_t)f2bf(h0) | ((uint_t)f2bf(h1) << 16);
      pk.y = (uint_t)f2bf(h2) | ((uint_t)f2bf(h3) << 16);
      *(uint2*)(ht + (t * 16 + m) * XSTRIDE + ch0 + quad * 4) = pk;
    }
  }
  __syncthreads();

#pragma unroll 1
  for (int p = 0; p < 2; ++p) {
    const int ch0 = (w + p * 4) * 16;
    bf16x8 wqf[4], wkf[4], wvf[4];
#pragma unroll
    for (int kb = 0; kb < 4; ++kb) {
      wqf[kb] = *(const bf16x8*)(wqb + (ch0 + m) * 128 + kb * 32 + quad * 8);
      wkf[kb] = *(const bf16x8*)(wkb + (ch0 + m) * 128 + kb * 32 + quad * 8);
      wvf[kb] = *(const bf16x8*)(wvb + (ch0 + m) * 128 + kb * 32 + quad * 8);
    }
    const float bqv = bq[ch0 + m];
    const float bkv = bk[ch0 + m];
    const float bvv = bv[ch0 + m];
#pragma unroll 1
    for (int t = 0; t < 4; ++t) {
      const ushort_t* hr = ht + (t * 16 + m) * XSTRIDE;
      bf16x8 af[4];
#pragma unroll
      for (int kb = 0; kb < 4; ++kb)
        af[kb] = *(const bf16x8*)(hr + kb * 32 + quad * 8);
      f32x4 qa = {0.f, 0.f, 0.f, 0.f};
      f32x4 ka = {0.f, 0.f, 0.f, 0.f};
#pragma unroll
      for (int kb = 0; kb < 4; ++kb) qa = mfma_bf16(af[kb], wqf[kb], qa);
#pragma unroll
      for (int kb = 0; kb < 4; ++kb) ka = mfma_bf16(af[kb], wkf[kb], ka);
      float p0 = (qa[0] + bqv) * (ka[0] + bkv);
      float p1 = (qa[1] + bqv) * (ka[1] + bkv);
      float p2 = (qa[2] + bqv) * (ka[2] + bkv);
      float p3 = (qa[3] + bqv) * (ka[3] + bkv);
      float mx = fmaxf(fmaxf(p0, p1), fmaxf(p2, p3));
      mx = fmaxf(mx, __shfl_xor(mx, 16));
      mx = fmaxf(mx, __shfl_xor(mx, 32));
      float e0 = __expf(p0 - mx), e1 = __expf(p1 - mx);
      float e2 = __expf(p2 - mx), e3 = __expf(p3 - mx);
      float sm = (e0 + e1) + (e2 + e3);
      sm += __shfl_xor(sm, 16);
      sm += __shfl_xor(sm, 32);
      f32x4 va = {0.f, 0.f, 0.f, 0.f};
#pragma unroll
      for (int kb = 0; kb < 4; ++kb) va = mfma_bf16(af[kb], wvf[kb], va);
      float r0 = e0 * (va[0] + bvv) + e1 * (va[1] + bvv) +
                 e2 * (va[2] + bvv) + e3 * (va[3] + bvv);
      r0 += __shfl_xor(r0, 16);
      r0 += __shfl_xor(r0, 32);
      if (quad == 0) souts[(ch0 + m) * 5 + t] = r0 / sm;
    }
  }
  __syncthreads();

  if (tid < 128) {
    const int c = tid;
    const size_t oi = ((size_t)b * NC + c) * NPOS + blockIdx.x * 4;
    const float4 xr = *(const float4*)(x_row + oi);
    const float* sp = souts + c * 5;
    float4 o;
    o.x = xr.x + g1 * sp[0];
    o.y = xr.y + g1 * sp[1];
    o.z = xr.z + g1 * sp[2];
    o.w = xr.w + g1 * sp[3];
    *(float4*)(out + oi) = o;
  }
}

extern "C" void kernel_launch(void* const* d_in, const int* in_sizes, int n_in,
                              void* d_out, int out_size, void* d_ws, size_t ws_size,
                              hipStream_t stream) {
  (void)in_sizes; (void)n_in; (void)out_size;
  const float* x_row   = (const float*)d_in[0];
  const float* x_local = (const float*)d_in[1];
  const float* w0   = (const float*)d_in[2];
  const float* bn_g = (const float*)d_in[4];
  const float* bn_b = (const float*)d_in[5];
  const float* wq   = (const float*)d_in[6];
  const float* bq   = (const float*)d_in[7];
  const float* wk   = (const float*)d_in[8];
  const float* bk   = (const float*)d_in[9];
  const float* wv   = (const float*)d_in[10];
  const float* bv   = (const float*)d_in[11];
  const float* gamma1 = (const float*)d_in[12];
  float* out = (float*)d_out;
  float* ws = (float*)d_ws;
  ushort_t* wb = (ushort_t*)((char*)d_ws + WSB_WEIGHTS);
  ushort_t* hg = (ushort_t*)((char*)d_ws + WSB_H);

  (void)hipMemsetAsync(ws, 0, 65536 * sizeof(float), stream);  // bucketed accumulators

  if (ws_size >= WS_NEEDED) {
    k_prep<1><<<256, 256, 0, stream>>>(w0, wq, wk, wv, wb);
    k_stats2<<<dim3(500, NB), 256, 0, stream>>>(x_local, wb, ws + WSF_SUMP,
                                                ws + WSF_SQP, hg);
    k_fold<<<1, 128, 0, stream>>>(ws, bn_g, bn_b, ws + WSF_ALPHA, ws + WSF_BETA);
    k_fused2<<<dim3(500, NB), 256, 0, stream>>>(hg, x_row, wb, ws + WSF_ALPHA,
                                                ws + WSF_BETA, bq, bk, bv, gamma1,
                                                out);
  } else {
    // workspace too small for the h buffer: previous verified pipeline
    k_prep<0><<<256, 256, 0, stream>>>(w0, wq, wk, wv, wb);
    k_stats1<<<dim3(250, NB), 256, 0, stream>>>(x_local, wb, ws + WSF_SUMP,
                                                ws + WSF_SQP);
    k_fold<<<1, 128, 0, stream>>>(ws, bn_g, bn_b, ws + WSF_ALPHA, ws + WSF_BETA);
    k_fused1<<<dim3(500, NB), 256, 0, stream>>>(x_local, x_row, wb, ws + WSF_ALPHA,
                                                ws + WSF_BETA, bq, bk, bv, gamma1,
                                                out);
  }
}

// Round 7
// 332.686 us; speedup vs baseline: 1.1556x; 1.1556x over previous
//
#include <hip/hip_runtime.h>
#include <math.h>

#define NB 8
#define NC 128
#define NPOS 2000
#define NK 32000
#define IN_EPS 1e-3f
#define BN_EPS 1e-5f

typedef short bf16x8 __attribute__((ext_vector_type(8)));
typedef _Float16 f16x8 __attribute__((ext_vector_type(8)));
typedef float f32x4 __attribute__((ext_vector_type(4)));
typedef unsigned short ushort_t;
typedef unsigned int uint_t;

// LDS row stride in ushorts (128 payload + 8 pad; keeps 16B alignment, 272B rows)
#define XSTRIDE 136

// ---- workspace layout ----
// [0 .. 32768)      sumP  : 32 buckets x (8b x 128c), bucket-major   (floats)
// [32768 .. 65536)  sqP
// [65536 .. 66560)  alpha
// [66560 .. 67584)  beta
// byte 270336:      weights w0,wq,wk,wv (16384 ushorts each; f16 on v2 path)
// byte 401408:      h buffer: [b][pos][136] fp16 (padded rows, 272B each)
#define WSF_SUMP  0
#define WSF_SQP   32768
#define WSF_ALPHA 65536
#define WSF_BETA  66560
#define WSB_WEIGHTS 270336
#define WSB_H     401408
#define WS_NEEDED ((size_t)WSB_H + (size_t)NB * NK * XSTRIDE * 2)

__device__ __forceinline__ f32x4 mfma_bf16(bf16x8 a, bf16x8 b, f32x4 c) {
  return __builtin_amdgcn_mfma_f32_16x16x32_bf16(a, b, c, 0, 0, 0);
}
__device__ __forceinline__ f32x4 mfma_f16(f16x8 a, f16x8 b, f32x4 c) {
  return __builtin_amdgcn_mfma_f32_16x16x32_f16(a, b, c, 0, 0, 0);
}

// fp32 -> bf16 round-to-nearest-even
__device__ __forceinline__ ushort_t f2bf(float f) {
  unsigned u = __float_as_uint(f);
  return (ushort_t)((u + 0x7FFFu + ((u >> 16) & 1u)) >> 16);
}
__device__ __forceinline__ ushort_t f2h(float f) {
  union { _Float16 h; ushort_t u; } cv;
  cv.h = (_Float16)f;
  return cv.u;
}
__device__ __forceinline__ float h2f(ushort_t u) {
  union { _Float16 h; ushort_t u; } cv;
  cv.u = u;
  return (float)cv.h;
}
// packed fp32x2 -> fp16x2 (round-toward-zero), single VALU op.
// NOTE: builtin returns __fp16 ext_vector(2); capture with auto + bit_cast.
__device__ __forceinline__ uint_t pk2h(float a, float b) {
  auto h = __builtin_amdgcn_cvt_pkrtz(a, b);
  return __builtin_bit_cast(uint_t, h);
}

// ---------------- K0: cast weights (ALL_F16: every matrix -> fp16; else bf16) ----------------
template <int ALL_F16>
__global__ __launch_bounds__(256) void k_prep(const float* __restrict__ w0,
    const float* __restrict__ wq, const float* __restrict__ wk,
    const float* __restrict__ wv, ushort_t* __restrict__ wb) {
  int idx = blockIdx.x * 256 + threadIdx.x;  // 0..65535
  int m = idx >> 14;
  int e = idx & 16383;
  const float* src = (m == 0) ? w0 : (m == 1) ? wq : (m == 2) ? wk : wv;
  float v = src[e];
  wb[m * 16384 + e] = ALL_F16 ? f2h(v) : f2bf(v);
}

// ---- staging (v1 fallback): Xt[col][cin] bf16, 128 columns ----
__device__ __forceinline__ void stage_xt128(const float* __restrict__ xb,
                                            ushort_t* __restrict__ xt, int tid) {
  const int col = tid & 127;
  const int hi = tid >> 7;  // 0/1
  const float* p = xb + col;
#pragma unroll
  for (int i = 0; i < 8; ++i) {
    const int c0 = hi * 64 + i * 8;
    ushort_t u[8] __attribute__((aligned(16)));
#pragma unroll
    for (int j = 0; j < 8; ++j) u[j] = f2bf(p[(size_t)(c0 + j) * NK]);
    *(uint4*)(xt + col * XSTRIDE + c0) = *(const uint4*)u;
  }
}

// ---- staging (v1 fallback): 64 columns, bf16 ----
__device__ __forceinline__ void stage_xt64(const float* __restrict__ xb,
                                           ushort_t* __restrict__ xt, int tid) {
  const int col = tid & 63;
  const int hi = tid >> 6;  // 0..3
  const float* p = xb + col;
#pragma unroll
  for (int i = 0; i < 4; ++i) {
    const int c0 = hi * 32 + i * 8;
    ushort_t u[8] __attribute__((aligned(16)));
#pragma unroll
    for (int j = 0; j < 8; ++j) u[j] = f2bf(p[(size_t)(c0 + j) * NK]);
    *(uint4*)(xt + col * XSTRIDE + c0) = *(const uint4*)u;
  }
}

// ---- staging v4: 64 columns, fp16 via v_cvt_pkrtz; 16 loads in flight per batch ----
__device__ __forceinline__ void stage_xt64_f16(const float* __restrict__ xb,
                                               ushort_t* __restrict__ xt, int tid) {
  const int col = tid & 63;
  const int hi = tid >> 6;  // 0..3 -> 32 channels each
  const float* p = xb + col;
#pragma unroll
  for (int r = 0; r < 2; ++r) {
    const int c0 = hi * 32 + r * 16;
    float v[16];
#pragma unroll
    for (int j = 0; j < 16; ++j) v[j] = p[(size_t)(c0 + j) * NK];
    uint_t u[8] __attribute__((aligned(16)));
#pragma unroll
    for (int j = 0; j < 8; ++j) u[j] = pk2h(v[2 * j], v[2 * j + 1]);
    *(uint4*)(xt + col * XSTRIDE + c0) = *(const uint4*)u;
    *(uint4*)(xt + col * XSTRIDE + c0 + 8) = *(const uint4*)(u + 4);
  }
}

// ---------------- K1 v4: conv (f16) + stats + materialize h (fp16, padded rows) ----------------
// 64-pos tile, 18.4KB LDS. Conv output kept in 16 regs (static idx); after the
// post-MFMA barrier the dead xt tile stages h so the global h-store is ONE
// contiguous 17,408B coalesced copy (full-line writes, no RFO).
// Stats computed from the fp16-ROUNDED h (keeps the BN-mean==0 identity in k_fold).
__global__ __launch_bounds__(256, 6) void k_stats2(const float* __restrict__ x,
    const ushort_t* __restrict__ w0b, float* __restrict__ sumP,
    float* __restrict__ sqP, ushort_t* __restrict__ hg) {
  __shared__ ushort_t xt[64 * XSTRIDE] __attribute__((aligned(16)));
  __shared__ float ssum[128], ssq[128];
  const int b = blockIdx.y;
  const int tid = threadIdx.x;
  stage_xt64_f16(x + (size_t)b * NC * NK + (size_t)blockIdx.x * 64, xt, tid);
  __syncthreads();
  const int lane = tid & 63, w = tid >> 6;
  const int m = lane & 15, quad = lane >> 4;

  uint2 hreg[8];  // [p*4+t], statically indexed (fully unrolled loops)

#pragma unroll
  for (int p = 0; p < 2; ++p) {
    const int ch0 = (w + p * 4) * 16;
    f16x8 wf[4];
#pragma unroll
    for (int kb = 0; kb < 4; ++kb)
      wf[kb] = *(const f16x8*)(w0b + (ch0 + m) * 128 + kb * 32 + quad * 8);
    float s0 = 0.f, s1 = 0.f, s2 = 0.f, s3 = 0.f;
    float q0 = 0.f, q1 = 0.f, q2 = 0.f, q3 = 0.f;
#pragma unroll
    for (int t = 0; t < 4; ++t) {
      const ushort_t* xr = xt + (t * 16 + m) * XSTRIDE;
      f32x4 acc = {0.f, 0.f, 0.f, 0.f};
#pragma unroll
      for (int kb = 0; kb < 4; ++kb) {
        f16x8 bx = *(const f16x8*)(xr + kb * 32 + quad * 8);
        acc = mfma_f16(wf[kb], bx, acc);
      }
      const ushort_t u0 = f2h(acc[0]), u1 = f2h(acc[1]);
      const ushort_t u2 = f2h(acc[2]), u3 = f2h(acc[3]);
      uint2 pk;
      pk.x = (uint_t)u0 | ((uint_t)u1 << 16);
      pk.y = (uint_t)u2 | ((uint_t)u3 << 16);
      hreg[p * 4 + t] = pk;
      const float r0 = h2f(u0), r1 = h2f(u1), r2 = h2f(u2), r3 = h2f(u3);
      s0 += r0; s1 += r1; s2 += r2; s3 += r3;
      q0 = fmaf(r0, r0, q0); q1 = fmaf(r1, r1, q1);
      q2 = fmaf(r2, r2, q2); q3 = fmaf(r3, r3, q3);
    }
    // positions live across the 16 m-lanes: butterfly over lane bits 0..3
#pragma unroll
    for (int d = 1; d < 16; d <<= 1) {
      s0 += __shfl_xor(s0, d); s1 += __shfl_xor(s1, d);
      s2 += __shfl_xor(s2, d); s3 += __shfl_xor(s3, d);
      q0 += __shfl_xor(q0, d); q1 += __shfl_xor(q1, d);
      q2 += __shfl_xor(q2, d); q3 += __shfl_xor(q3, d);
    }
    if (m == 0) {  // strips disjoint across (w,p,quad) -> plain stores
      ssum[ch0 + quad * 4 + 0] = s0; ssum[ch0 + quad * 4 + 1] = s1;
      ssum[ch0 + quad * 4 + 2] = s2; ssum[ch0 + quad * 4 + 3] = s3;
      ssq[ch0 + quad * 4 + 0] = q0; ssq[ch0 + quad * 4 + 1] = q1;
      ssq[ch0 + quad * 4 + 2] = q2; ssq[ch0 + quad * 4 + 3] = q3;
    }
  }
  __syncthreads();  // all xt reads done; ssum/ssq visible

  // phase C: scatter h fragments into the dead xt tile (LDS, cheap)
#pragma unroll
  for (int p = 0; p < 2; ++p) {
    const int ch0 = (w + p * 4) * 16;
#pragma unroll
    for (int t = 0; t < 4; ++t)
      *(uint2*)(xt + (t * 16 + m) * XSTRIDE + ch0 + quad * 4) = hreg[p * 4 + t];
  }
  __syncthreads();

  // phase D: one contiguous coalesced 17,408B store LDS -> global
  {
    const uint4* src = (const uint4*)xt;
    uint4* dst =
        (uint4*)(hg + ((size_t)b * NK + (size_t)blockIdx.x * 64) * XSTRIDE);
#pragma unroll
    for (int i = 0; i < 4; ++i) dst[i * 256 + tid] = src[i * 256 + tid];
    if (tid < 64) dst[1024 + tid] = src[1024 + tid];
  }

  if (tid < 128) {
    const int bucket = blockIdx.x & 31;
    atomicAdd(&sumP[bucket * 1024 + b * 128 + tid], ssum[tid]);
    atomicAdd(&sqP[bucket * 1024 + b * 128 + tid], ssq[tid]);
  }
}

// ---------------- K2: reduce buckets, fold IN+BN into per-(b,c) alpha/beta ----------------
__global__ void k_fold(const float* __restrict__ ws_in, const float* __restrict__ bn_g,
                       const float* __restrict__ bn_b, float* __restrict__ alpha,
                       float* __restrict__ beta) {
  int c = threadIdx.x;  // 128 threads
  const float* sumP = ws_in + WSF_SUMP;
  const float* sqP = ws_in + WSF_SQP;
  float var[NB], muv[NB];
  float bvar = 0.f;
#pragma unroll 1
  for (int b = 0; b < NB; ++b) {
    float s = 0.f, q = 0.f;
#pragma unroll
    for (int k = 0; k < 32; ++k) {
      s += sumP[k * 1024 + b * 128 + c];
      q += sqP[k * 1024 + b * 128 + c];
    }
    float mu = s * (1.f / NK);
    float v = q * (1.f / NK) - mu * mu;
    muv[b] = mu;
    var[b] = v;
    bvar += v / (v + IN_EPS);
  }
  bvar *= 0.125f;
  float s2 = rsqrtf(bvar + BN_EPS);
  float g = bn_g[c], bb = bn_b[c];
#pragma unroll
  for (int b = 0; b < NB; ++b) {
    float a = rsqrtf(var[b] + IN_EPS) * s2 * g;
    alpha[b * 128 + c] = a;
    beta[b * 128 + c] = bb - muv[b] * a;
  }
}

// normalize 2 packed fp16 with per-channel alpha/beta + relu, repack (1 cvt op out)
__device__ __forceinline__ uint_t norm2(uint_t hv, float a0, float a1, float c0,
                                        float c1) {
  float lo = h2f((ushort_t)(hv & 0xffffu));
  float hi = h2f((ushort_t)(hv >> 16));
  return pk2h(fmaxf(fmaf(lo, a0, c0), 0.f), fmaxf(fmaf(hi, a1, c1), 0.f));
}

// ---------------- K3 v6: load h (+norm fused in staging) -> qkv+softmax+agg ----------------
// launch_bounds(256,6): VGPR budget 512/6=85 >= the ~52 the QKV phase needs ->
// no spills (the (256,8) experiment capped at 64: VGPR squeezed to 32, 235MB of
// scratch spill traffic, dur 79->153us). 6 blocks/CU (LDS 6x19,968=120KB).
__global__ __launch_bounds__(256, 6) void k_fused2(
    const ushort_t* __restrict__ hg, const float* __restrict__ x_row,
    const ushort_t* __restrict__ wb, const float* __restrict__ alpha,
    const float* __restrict__ beta, const float* __restrict__ bq,
    const float* __restrict__ bk, const float* __restrict__ bv,
    const float* __restrict__ g1p, float* __restrict__ out) {
  __shared__ ushort_t xt[64 * XSTRIDE] __attribute__((aligned(16)));  // 17408 B
  __shared__ float souts[128 * 5];                                    // 2560 B
  const int b = blockIdx.y;
  const int tid = threadIdx.x;
  const int lane = tid & 63, w = tid >> 6;

  // hoist epilogue x_row load (independent; hides HBM latency under QKV)
  const size_t oi = ((size_t)b * NC + tid) * NPOS + blockIdx.x * 4;
  float4 xr_early;
  if (tid < 128) xr_early = *(const float4*)(x_row + oi);

  // stage + fused norm: 1088 uint4 chunks (17,408 B). Row = j/17; chunk c=j%17
  // covers channels c*8..c*8+7 (c==16 is the 16B pad -> raw copy).
  {
    const uint4* src =
        (const uint4*)(hg + ((size_t)b * NK + (size_t)blockIdx.x * 64) * XSTRIDE);
    uint4* dst = (uint4*)xt;
    const float* ap = alpha + b * 128;
    const float* bp = beta + b * 128;
#pragma unroll
    for (int i = 0; i < 5; ++i) {
      if (i < 4 || tid < 64) {
        const int j = i * 256 + tid;
        uint4 v = src[j];
        const int c = j % 17;
        if (c < 16) {
          const int ch = c * 8;
          const float4 a0 = *(const float4*)(ap + ch);
          const float4 a1 = *(const float4*)(ap + ch + 4);
          const float4 c0 = *(const float4*)(bp + ch);
          const float4 c1 = *(const float4*)(bp + ch + 4);
          v.x = norm2(v.x, a0.x, a0.y, c0.x, c0.y);
          v.y = norm2(v.y, a0.z, a0.w, c0.z, c0.w);
          v.z = norm2(v.z, a1.x, a1.y, c1.x, c1.y);
          v.w = norm2(v.w, a1.z, a1.w, c1.z, c1.w);
        }
        dst[j] = v;
      }
    }
  }
  const float g1 = g1p[0];
  __syncthreads();

  // ---- QKV phase (fp16) ----
  const int m = lane & 15, quad = lane >> 4;
  const ushort_t* wqb = wb + 16384;
  const ushort_t* wkb = wb + 32768;
  const ushort_t* wvb = wb + 49152;
#pragma unroll 1
  for (int p = 0; p < 2; ++p) {
    const int ch0 = (w + p * 4) * 16;
    f16x8 wqf[4], wkf[4], wvf[4];
#pragma unroll
    for (int kb = 0; kb < 4; ++kb) {
      wqf[kb] = *(const f16x8*)(wqb + (ch0 + m) * 128 + kb * 32 + quad * 8);
      wkf[kb] = *(const f16x8*)(wkb + (ch0 + m) * 128 + kb * 32 + quad * 8);
      wvf[kb] = *(const f16x8*)(wvb + (ch0 + m) * 128 + kb * 32 + quad * 8);
    }
    const float bqv = bq[ch0 + m];
    const float bkv = bk[ch0 + m];
    const float bvv = bv[ch0 + m];
#pragma unroll 1
    for (int t = 0; t < 4; ++t) {
      const ushort_t* hr = xt + (t * 16 + m) * XSTRIDE;
      f16x8 af[4];
#pragma unroll
      for (int kb = 0; kb < 4; ++kb)
        af[kb] = *(const f16x8*)(hr + kb * 32 + quad * 8);
      f32x4 qa = {0.f, 0.f, 0.f, 0.f};
      f32x4 ka = {0.f, 0.f, 0.f, 0.f};
#pragma unroll
      for (int kb = 0; kb < 4; ++kb) qa = mfma_f16(af[kb], wqf[kb], qa);
#pragma unroll
      for (int kb = 0; kb < 4; ++kb) ka = mfma_f16(af[kb], wkf[kb], ka);
      // D: col=lane&15 -> outch-in-strip, row=quad*4+r -> neighbor
      float p0 = (qa[0] + bqv) * (ka[0] + bkv);
      float p1 = (qa[1] + bqv) * (ka[1] + bkv);
      float p2 = (qa[2] + bqv) * (ka[2] + bkv);
      float p3 = (qa[3] + bqv) * (ka[3] + bkv);
      float mx = fmaxf(fmaxf(p0, p1), fmaxf(p2, p3));
      mx = fmaxf(mx, __shfl_xor(mx, 16));
      mx = fmaxf(mx, __shfl_xor(mx, 32));
      float e0 = __expf(p0 - mx), e1 = __expf(p1 - mx);
      float e2 = __expf(p2 - mx), e3 = __expf(p3 - mx);
      float sm = (e0 + e1) + (e2 + e3);
      sm += __shfl_xor(sm, 16);
      sm += __shfl_xor(sm, 32);
      f32x4 va = {0.f, 0.f, 0.f, 0.f};
#pragma unroll
      for (int kb = 0; kb < 4; ++kb) va = mfma_f16(af[kb], wvf[kb], va);
      // sum_k e_k*(v_k+bv) = sum e_k*v_k + bv*sum e_k  ->  add bv after divide
      float r0 = e0 * va[0] + e1 * va[1] + e2 * va[2] + e3 * va[3];
      r0 += __shfl_xor(r0, 16);
      r0 += __shfl_xor(r0, 32);
      if (quad == 0) souts[(ch0 + m) * 5 + t] = r0 / sm + bvv;
    }
  }
  __syncthreads();

  // ---- coalesced epilogue: out = x_row + g1 * souts ----
  if (tid < 128) {
    const float* sp = souts + tid * 5;
    float4 o;
    o.x = xr_early.x + g1 * sp[0];
    o.y = xr_early.y + g1 * sp[1];
    o.z = xr_early.z + g1 * sp[2];
    o.w = xr_early.w + g1 * sp[3];
    *(float4*)(out + oi) = o;
  }
}

// =================== v1 fallback path (used only if workspace too small) ===================
__global__ __launch_bounds__(256, 4) void k_stats1(const float* __restrict__ x,
    const ushort_t* __restrict__ w0b, float* __restrict__ sumP,
    float* __restrict__ sqP) {
  __shared__ ushort_t xt[128 * XSTRIDE];
  __shared__ float ssum[128], ssq[128];
  const int b = blockIdx.y;
  const int tid = threadIdx.x;
  stage_xt128(x + (size_t)b * NC * NK + (size_t)blockIdx.x * 128, xt, tid);
  __syncthreads();
  const int lane = tid & 63, w = tid >> 6;
  const int m = lane & 15, quad = lane >> 4;

#pragma unroll 1
  for (int p = 0; p < 2; ++p) {
    const int ch0 = (w + p * 4) * 16;
    bf16x8 wf[4];
#pragma unroll
    for (int kb = 0; kb < 4; ++kb)
      wf[kb] = *(const bf16x8*)(w0b + (ch0 + m) * 128 + kb * 32 + quad * 8);
    float s = 0.f, q2 = 0.f;
#pragma unroll 2
    for (int t = 0; t < 8; ++t) {
      const ushort_t* xr = xt + (t * 16 + m) * XSTRIDE;
      f32x4 acc = {0.f, 0.f, 0.f, 0.f};
#pragma unroll
      for (int kb = 0; kb < 4; ++kb) {
        bf16x8 af = *(const bf16x8*)(xr + kb * 32 + quad * 8);
        acc = mfma_bf16(af, wf[kb], acc);
      }
      s += (acc[0] + acc[1]) + (acc[2] + acc[3]);
      q2 += (acc[0] * acc[0] + acc[1] * acc[1]) +
            (acc[2] * acc[2] + acc[3] * acc[3]);
    }
    s += __shfl_xor(s, 16);
    s += __shfl_xor(s, 32);
    q2 += __shfl_xor(q2, 16);
    q2 += __shfl_xor(q2, 32);
    if (quad == 0) {
      ssum[ch0 + m] = s;
      ssq[ch0 + m] = q2;
    }
  }
  __syncthreads();
  if (tid < 128) {
    const int bucket = blockIdx.x & 31;
    atomicAdd(&sumP[bucket * 1024 + b * 128 + tid], ssum[tid]);
    atomicAdd(&sqP[bucket * 1024 + b * 128 + tid], ssq[tid]);
  }
}

__global__ __launch_bounds__(256, 4) void k_fused1(const float* __restrict__ x,
    const float* __restrict__ x_row, const ushort_t* __restrict__ wb,
    const float* __restrict__ alpha, const float* __restrict__ beta,
    const float* __restrict__ bq, const float* __restrict__ bk,
    const float* __restrict__ bv, const float* __restrict__ g1p,
    float* __restrict__ out) {
  __shared__ ushort_t xt[64 * XSTRIDE];
  __shared__ ushort_t ht[64 * XSTRIDE];
  __shared__ float souts[128 * 5];
  const int b = blockIdx.y;
  const int tid = threadIdx.x;
  stage_xt64(x + (size_t)b * NC * NK + (size_t)blockIdx.x * 64, xt, tid);
  const float g1 = g1p[0];
  __syncthreads();
  const int lane = tid & 63, w = tid >> 6;
  const int m = lane & 15, quad = lane >> 4;
  const ushort_t* w0b = wb;
  const ushort_t* wqb = wb + 16384;
  const ushort_t* wkb = wb + 32768;
  const ushort_t* wvb = wb + 49152;

#pragma unroll 1
  for (int p = 0; p < 2; ++p) {
    const int ch0 = (w + p * 4) * 16;
    bf16x8 wf[4];
#pragma unroll
    for (int kb = 0; kb < 4; ++kb)
      wf[kb] = *(const bf16x8*)(w0b + (ch0 + m) * 128 + kb * 32 + quad * 8);
    const float4 av = *(const float4*)(alpha + b * 128 + ch0 + quad * 4);
    const float4 bev = *(const float4*)(beta + b * 128 + ch0 + quad * 4);
#pragma unroll
    for (int t = 0; t < 4; ++t) {
      const ushort_t* xr = xt + (t * 16 + m) * XSTRIDE;
      f32x4 acc = {0.f, 0.f, 0.f, 0.f};
#pragma unroll
      for (int kb = 0; kb < 4; ++kb) {
        bf16x8 bx = *(const bf16x8*)(xr + kb * 32 + quad * 8);
        acc = mfma_bf16(wf[kb], bx, acc);
      }
      float h0 = fmaxf(acc[0] * av.x + bev.x, 0.f);
      float h1 = fmaxf(acc[1] * av.y + bev.y, 0.f);
      float h2 = fmaxf(acc[2] * av.z + bev.z, 0.f);
      float h3 = fmaxf(acc[3] * av.w + bev.w, 0.f);
      uint2 pk;
      pk.x = (uint_t)f2bf(h0) | ((uint_t)f2bf(h1) << 16);
      pk.y = (uint_t)f2bf(h2) | ((uint_t)f2bf(h3) << 16);
      *(uint2*)(ht + (t * 16 + m) * XSTRIDE + ch0 + quad * 4) = pk;
    }
  }
  __syncthreads();

#pragma unroll 1
  for (int p = 0; p < 2; ++p) {
    const int ch0 = (w + p * 4) * 16;
    bf16x8 wqf[4], wkf[4], wvf[4];
#pragma unroll
    for (int kb = 0; kb < 4; ++kb) {
      wqf[kb] = *(const bf16x8*)(wqb + (ch0 + m) * 128 + kb * 32 + quad * 8);
      wkf[kb] = *(const bf16x8*)(wkb + (ch0 + m) * 128 + kb * 32 + quad * 8);
      wvf[kb] = *(const bf16x8*)(wvb + (ch0 + m) * 128 + kb * 32 + quad * 8);
    }
    const float bqv = bq[ch0 + m];
    const float bkv = bk[ch0 + m];
    const float bvv = bv[ch0 + m];
#pragma unroll 1
    for (int t = 0; t < 4; ++t) {
      const ushort_t* hr = ht + (t * 16 + m) * XSTRIDE;
      bf16x8 af[4];
#pragma unroll
      for (int kb = 0; kb < 4; ++kb)
        af[kb] = *(const bf16x8*)(hr + kb * 32 + quad * 8);
      f32x4 qa = {0.f, 0.f, 0.f, 0.f};
      f32x4 ka = {0.f, 0.f, 0.f, 0.f};
#pragma unroll
      for (int kb = 0; kb < 4; ++kb) qa = mfma_bf16(af[kb], wqf[kb], qa);
#pragma unroll
      for (int kb = 0; kb < 4; ++kb) ka = mfma_bf16(af[kb], wkf[kb], ka);
      float p0 = (qa[0] + bqv) * (ka[0] + bkv);
      float p1 = (qa[1] + bqv) * (ka[1] + bkv);
      float p2 = (qa[2] + bqv) * (ka[2] + bkv);
      float p3 = (qa[3] + bqv) * (ka[3] + bkv);
      float mx = fmaxf(fmaxf(p0, p1), fmaxf(p2, p3));
      mx = fmaxf(mx, __shfl_xor(mx, 16));
      mx = fmaxf(mx, __shfl_xor(mx, 32));
      float e0 = __expf(p0 - mx), e1 = __expf(p1 - mx);
      float e2 = __expf(p2 - mx), e3 = __expf(p3 - mx);
      float sm = (e0 + e1) + (e2 + e3);
      sm += __shfl_xor(sm, 16);
      sm += __shfl_xor(sm, 32);
      f32x4 va = {0.f, 0.f, 0.f, 0.f};
#pragma unroll
      for (int kb = 0; kb < 4; ++kb) va = mfma_bf16(af[kb], wvf[kb], va);
      float r0 = e0 * (va[0] + bvv) + e1 * (va[1] + bvv) +
                 e2 * (va[2] + bvv) + e3 * (va[3] + bvv);
      r0 += __shfl_xor(r0, 16);
      r0 += __shfl_xor(r0, 32);
      if (quad == 0) souts[(ch0 + m) * 5 + t] = r0 / sm;
    }
  }
  __syncthreads();

  if (tid < 128) {
    const int c = tid;
    const size_t oi = ((size_t)b * NC + c) * NPOS + blockIdx.x * 4;
    const float4 xr = *(const float4*)(x_row + oi);
    const float* sp = souts + c * 5;
    float4 o;
    o.x = xr.x + g1 * sp[0];
    o.y = xr.y + g1 * sp[1];
    o.z = xr.z + g1 * sp[2];
    o.w = xr.w + g1 * sp[3];
    *(float4*)(out + oi) = o;
  }
}

extern "C" void kernel_launch(void* const* d_in, const int* in_sizes, int n_in,
                              void* d_out, int out_size, void* d_ws, size_t ws_size,
                              hipStream_t stream) {
  (void)in_sizes; (void)n_in; (void)out_size;
  const float* x_row   = (const float*)d_in[0];
  const float* x_local = (const float*)d_in[1];
  const float* w0   = (const float*)d_in[2];
  const float* bn_g = (const float*)d_in[4];
  const float* bn_b = (const float*)d_in[5];
  const float* wq   = (const float*)d_in[6];
  const float* bq   = (const float*)d_in[7];
  const float* wk   = (const float*)d_in[8];
  const float* bk   = (const float*)d_in[9];
  const float* wv   = (const float*)d_in[10];
  const float* bv   = (const float*)d_in[11];
  const float* gamma1 = (const float*)d_in[12];
  float* out = (float*)d_out;
  float* ws = (float*)d_ws;
  ushort_t* wb = (ushort_t*)((char*)d_ws + WSB_WEIGHTS);
  ushort_t* hg = (ushort_t*)((char*)d_ws + WSB_H);

  (void)hipMemsetAsync(ws, 0, 65536 * sizeof(float), stream);  // bucketed accumulators

  if (ws_size >= WS_NEEDED) {
    k_prep<1><<<256, 256, 0, stream>>>(w0, wq, wk, wv, wb);
    k_stats2<<<dim3(500, NB), 256, 0, stream>>>(x_local, wb, ws + WSF_SUMP,
                                                ws + WSF_SQP, hg);
    k_fold<<<1, 128, 0, stream>>>(ws, bn_g, bn_b, ws + WSF_ALPHA, ws + WSF_BETA);
    k_fused2<<<dim3(500, NB), 256, 0, stream>>>(hg, x_row, wb, ws + WSF_ALPHA,
                                                ws + WSF_BETA, bq, bk, bv, gamma1,
                                                out);
  } else {
    // workspace too small for the h buffer: previous verified pipeline
    k_prep<0><<<256, 256, 0, stream>>>(w0, wq, wk, wv, wb);
    k_stats1<<<dim3(250, NB), 256, 0, stream>>>(x_local, wb, ws + WSF_SUMP,
                                                ws + WSF_SQP);
    k_fold<<<1, 128, 0, stream>>>(ws, bn_g, bn_b, ws + WSF_ALPHA, ws + WSF_BETA);
    k_fused1<<<dim3(500, NB), 256, 0, stream>>>(x_local, x_row, wb, ws + WSF_ALPHA,
                                                ws + WSF_BETA, bq, bk, bv, gamma1,
                                                out);
  }
}

// Round 8
// 319.149 us; speedup vs baseline: 1.2046x; 1.0424x over previous
//
#include <hip/hip_runtime.h>
#include <math.h>

#define NB 8
#define NC 128
#define NPOS 2000
#define NK 32000
#define IN_EPS 1e-3f
#define BN_EPS 1e-5f

typedef short bf16x8 __attribute__((ext_vector_type(8)));
typedef _Float16 f16x8 __attribute__((ext_vector_type(8)));
typedef float f32x4 __attribute__((ext_vector_type(4)));
typedef unsigned short ushort_t;
typedef unsigned int uint_t;

// LDS row stride in ushorts (128 payload + 8 pad; keeps 16B alignment, 272B rows)
#define XSTRIDE 136
#define SOUTS 9  // 8 positions + 1 pad

// ---- workspace layout ----
#define WSF_SUMP  0
#define WSF_SQP   32768
#define WSF_ALPHA 65536
#define WSF_BETA  66560
#define WSB_WEIGHTS 270336
#define WSB_H     401408
#define WS_NEEDED ((size_t)WSB_H + (size_t)NB * NK * XSTRIDE * 2)

__device__ __forceinline__ f32x4 mfma_bf16(bf16x8 a, bf16x8 b, f32x4 c) {
  return __builtin_amdgcn_mfma_f32_16x16x32_bf16(a, b, c, 0, 0, 0);
}
__device__ __forceinline__ f32x4 mfma_f16(f16x8 a, f16x8 b, f32x4 c) {
  return __builtin_amdgcn_mfma_f32_16x16x32_f16(a, b, c, 0, 0, 0);
}

__device__ __forceinline__ ushort_t f2bf(float f) {
  unsigned u = __float_as_uint(f);
  return (ushort_t)((u + 0x7FFFu + ((u >> 16) & 1u)) >> 16);
}
__device__ __forceinline__ ushort_t f2h(float f) {
  union { _Float16 h; ushort_t u; } cv;
  cv.h = (_Float16)f;
  return cv.u;
}
__device__ __forceinline__ float h2f(ushort_t u) {
  union { _Float16 h; ushort_t u; } cv;
  cv.u = u;
  return (float)cv.h;
}
__device__ __forceinline__ uint_t pk2h(float a, float b) {
  auto h = __builtin_amdgcn_cvt_pkrtz(a, b);
  return __builtin_bit_cast(uint_t, h);
}

// ---------------- K0: cast weights ----------------
template <int ALL_F16>
__global__ __launch_bounds__(256) void k_prep(const float* __restrict__ w0,
    const float* __restrict__ wq, const float* __restrict__ wk,
    const float* __restrict__ wv, ushort_t* __restrict__ wb) {
  int idx = blockIdx.x * 256 + threadIdx.x;  // 0..65535
  int m = idx >> 14;
  int e = idx & 16383;
  const float* src = (m == 0) ? w0 : (m == 1) ? wq : (m == 2) ? wk : wv;
  float v = src[e];
  wb[m * 16384 + e] = ALL_F16 ? f2h(v) : f2bf(v);
}

// ---- staging (v1 fallback): Xt[col][cin] bf16, 128 columns ----
__device__ __forceinline__ void stage_xt128(const float* __restrict__ xb,
                                            ushort_t* __restrict__ xt, int tid) {
  const int col = tid & 127;
  const int hi = tid >> 7;
  const float* p = xb + col;
#pragma unroll
  for (int i = 0; i < 8; ++i) {
    const int c0 = hi * 64 + i * 8;
    ushort_t u[8] __attribute__((aligned(16)));
#pragma unroll
    for (int j = 0; j < 8; ++j) u[j] = f2bf(p[(size_t)(c0 + j) * NK]);
    *(uint4*)(xt + col * XSTRIDE + c0) = *(const uint4*)u;
  }
}

// ---- staging (v1 fallback): 64 columns, bf16 ----
__device__ __forceinline__ void stage_xt64(const float* __restrict__ xb,
                                           ushort_t* __restrict__ xt, int tid) {
  const int col = tid & 63;
  const int hi = tid >> 6;
  const float* p = xb + col;
#pragma unroll
  for (int i = 0; i < 4; ++i) {
    const int c0 = hi * 32 + i * 8;
    ushort_t u[8] __attribute__((aligned(16)));
#pragma unroll
    for (int j = 0; j < 8; ++j) u[j] = f2bf(p[(size_t)(c0 + j) * NK]);
    *(uint4*)(xt + col * XSTRIDE + c0) = *(const uint4*)u;
  }
}

// ---- staging v4: 64 columns, fp16 via v_cvt_pkrtz ----
__device__ __forceinline__ void stage_xt64_f16(const float* __restrict__ xb,
                                               ushort_t* __restrict__ xt, int tid) {
  const int col = tid & 63;
  const int hi = tid >> 6;
  const float* p = xb + col;
#pragma unroll
  for (int r = 0; r < 2; ++r) {
    const int c0 = hi * 32 + r * 16;
    float v[16];
#pragma unroll
    for (int j = 0; j < 16; ++j) v[j] = p[(size_t)(c0 + j) * NK];
    uint_t u[8] __attribute__((aligned(16)));
#pragma unroll
    for (int j = 0; j < 8; ++j) u[j] = pk2h(v[2 * j], v[2 * j + 1]);
    *(uint4*)(xt + col * XSTRIDE + c0) = *(const uint4*)u;
    *(uint4*)(xt + col * XSTRIDE + c0 + 8) = *(const uint4*)(u + 4);
  }
}

// ---------------- K1 v4: conv (f16) + stats + materialize h ----------------
__global__ __launch_bounds__(256, 6) void k_stats2(const float* __restrict__ x,
    const ushort_t* __restrict__ w0b, float* __restrict__ sumP,
    float* __restrict__ sqP, ushort_t* __restrict__ hg) {
  __shared__ ushort_t xt[64 * XSTRIDE] __attribute__((aligned(16)));
  __shared__ float ssum[128], ssq[128];
  const int b = blockIdx.y;
  const int tid = threadIdx.x;
  stage_xt64_f16(x + (size_t)b * NC * NK + (size_t)blockIdx.x * 64, xt, tid);
  __syncthreads();
  const int lane = tid & 63, w = tid >> 6;
  const int m = lane & 15, quad = lane >> 4;

  uint2 hreg[8];  // [p*4+t], statically indexed

#pragma unroll
  for (int p = 0; p < 2; ++p) {
    const int ch0 = (w + p * 4) * 16;
    f16x8 wf[4];
#pragma unroll
    for (int kb = 0; kb < 4; ++kb)
      wf[kb] = *(const f16x8*)(w0b + (ch0 + m) * 128 + kb * 32 + quad * 8);
    float s0 = 0.f, s1 = 0.f, s2 = 0.f, s3 = 0.f;
    float q0 = 0.f, q1 = 0.f, q2 = 0.f, q3 = 0.f;
#pragma unroll
    for (int t = 0; t < 4; ++t) {
      const ushort_t* xr = xt + (t * 16 + m) * XSTRIDE;
      f32x4 acc = {0.f, 0.f, 0.f, 0.f};
#pragma unroll
      for (int kb = 0; kb < 4; ++kb) {
        f16x8 bx = *(const f16x8*)(xr + kb * 32 + quad * 8);
        acc = mfma_f16(wf[kb], bx, acc);
      }
      const ushort_t u0 = f2h(acc[0]), u1 = f2h(acc[1]);
      const ushort_t u2 = f2h(acc[2]), u3 = f2h(acc[3]);
      uint2 pk;
      pk.x = (uint_t)u0 | ((uint_t)u1 << 16);
      pk.y = (uint_t)u2 | ((uint_t)u3 << 16);
      hreg[p * 4 + t] = pk;
      const float r0 = h2f(u0), r1 = h2f(u1), r2 = h2f(u2), r3 = h2f(u3);
      s0 += r0; s1 += r1; s2 += r2; s3 += r3;
      q0 = fmaf(r0, r0, q0); q1 = fmaf(r1, r1, q1);
      q2 = fmaf(r2, r2, q2); q3 = fmaf(r3, r3, q3);
    }
#pragma unroll
    for (int d = 1; d < 16; d <<= 1) {
      s0 += __shfl_xor(s0, d); s1 += __shfl_xor(s1, d);
      s2 += __shfl_xor(s2, d); s3 += __shfl_xor(s3, d);
      q0 += __shfl_xor(q0, d); q1 += __shfl_xor(q1, d);
      q2 += __shfl_xor(q2, d); q3 += __shfl_xor(q3, d);
    }
    if (m == 0) {
      ssum[ch0 + quad * 4 + 0] = s0; ssum[ch0 + quad * 4 + 1] = s1;
      ssum[ch0 + quad * 4 + 2] = s2; ssum[ch0 + quad * 4 + 3] = s3;
      ssq[ch0 + quad * 4 + 0] = q0; ssq[ch0 + quad * 4 + 1] = q1;
      ssq[ch0 + quad * 4 + 2] = q2; ssq[ch0 + quad * 4 + 3] = q3;
    }
  }
  __syncthreads();

#pragma unroll
  for (int p = 0; p < 2; ++p) {
    const int ch0 = (w + p * 4) * 16;
#pragma unroll
    for (int t = 0; t < 4; ++t)
      *(uint2*)(xt + (t * 16 + m) * XSTRIDE + ch0 + quad * 4) = hreg[p * 4 + t];
  }
  __syncthreads();

  {
    const uint4* src = (const uint4*)xt;
    uint4* dst =
        (uint4*)(hg + ((size_t)b * NK + (size_t)blockIdx.x * 64) * XSTRIDE);
#pragma unroll
    for (int i = 0; i < 4; ++i) dst[i * 256 + tid] = src[i * 256 + tid];
    if (tid < 64) dst[1024 + tid] = src[1024 + tid];
  }

  if (tid < 128) {
    const int bucket = blockIdx.x & 31;
    atomicAdd(&sumP[bucket * 1024 + b * 128 + tid], ssum[tid]);
    atomicAdd(&sqP[bucket * 1024 + b * 128 + tid], ssq[tid]);
  }
}

// ---------------- K2: fold IN+BN into per-(b,c) alpha/beta ----------------
__global__ void k_fold(const float* __restrict__ ws_in, const float* __restrict__ bn_g,
                       const float* __restrict__ bn_b, float* __restrict__ alpha,
                       float* __restrict__ beta) {
  int c = threadIdx.x;  // 128 threads
  const float* sumP = ws_in + WSF_SUMP;
  const float* sqP = ws_in + WSF_SQP;
  float var[NB], muv[NB];
  float bvar = 0.f;
#pragma unroll 1
  for (int b = 0; b < NB; ++b) {
    float s = 0.f, q = 0.f;
#pragma unroll
    for (int k = 0; k < 32; ++k) {
      s += sumP[k * 1024 + b * 128 + c];
      q += sqP[k * 1024 + b * 128 + c];
    }
    float mu = s * (1.f / NK);
    float v = q * (1.f / NK) - mu * mu;
    muv[b] = mu;
    var[b] = v;
    bvar += v / (v + IN_EPS);
  }
  bvar *= 0.125f;
  float s2 = rsqrtf(bvar + BN_EPS);
  float g = bn_g[c], bb = bn_b[c];
#pragma unroll
  for (int b = 0; b < NB; ++b) {
    float a = rsqrtf(var[b] + IN_EPS) * s2 * g;
    alpha[b * 128 + c] = a;
    beta[b * 128 + c] = bb - muv[b] * a;
  }
}

__device__ __forceinline__ uint_t norm2(uint_t hv, float a0, float a1, float c0,
                                        float c1) {
  float lo = h2f((ushort_t)(hv & 0xffffu));
  float hi = h2f((ushort_t)(hv >> 16));
  return pk2h(fmaxf(fmaf(lo, a0, c0), 0.f), fmaxf(fmaf(hi, a1, c1), 0.f));
}

// ---- fused3 helpers: 64-col tile = 1088 uint4s, per-thread regs v[0..4] ----
__device__ __forceinline__ void tile_load(const uint4* __restrict__ src, int tid,
                                          uint4 v[5]) {
#pragma unroll
  for (int i = 0; i < 4; ++i) v[i] = src[i * 256 + tid];
  if (tid < 64) v[4] = src[1024 + tid];
}

__device__ __forceinline__ void tile_norm_store(const uint4 v[5],
                                                ushort_t* __restrict__ xt, int tid,
                                                const float* __restrict__ ap,
                                                const float* __restrict__ bp) {
#pragma unroll
  for (int i = 0; i < 5; ++i) {
    if (i < 4 || tid < 64) {
      const int j = i * 256 + tid;
      uint4 t = v[i];
      const int c = j % 17;
      if (c < 16) {
        const int ch = c * 8;
        const float4 a0 = *(const float4*)(ap + ch);
        const float4 a1 = *(const float4*)(ap + ch + 4);
        const float4 c0 = *(const float4*)(bp + ch);
        const float4 c1 = *(const float4*)(bp + ch + 4);
        t.x = norm2(t.x, a0.x, a0.y, c0.x, c0.y);
        t.y = norm2(t.y, a0.z, a0.w, c0.z, c0.w);
        t.z = norm2(t.z, a1.x, a1.y, c1.x, c1.y);
        t.w = norm2(t.w, a1.z, a1.w, c1.z, c1.w);
      }
      ((uint4*)xt)[j] = t;
    }
  }
}

__device__ __forceinline__ void qkv_phase(const ushort_t* __restrict__ xt,
    float* __restrict__ souts, const ushort_t* __restrict__ wqb,
    const ushort_t* __restrict__ wkb, const ushort_t* __restrict__ wvb,
    const float* __restrict__ bq, const float* __restrict__ bk,
    const float* __restrict__ bv, int w, int m, int quad, int tbase) {
#pragma unroll 1
  for (int p = 0; p < 2; ++p) {
    const int ch0 = (w + p * 4) * 16;
    f16x8 wqf[4], wkf[4], wvf[4];
#pragma unroll
    for (int kb = 0; kb < 4; ++kb) {
      wqf[kb] = *(const f16x8*)(wqb + (ch0 + m) * 128 + kb * 32 + quad * 8);
      wkf[kb] = *(const f16x8*)(wkb + (ch0 + m) * 128 + kb * 32 + quad * 8);
      wvf[kb] = *(const f16x8*)(wvb + (ch0 + m) * 128 + kb * 32 + quad * 8);
    }
    const float bqv = bq[ch0 + m];
    const float bkv = bk[ch0 + m];
    const float bvv = bv[ch0 + m];
#pragma unroll 1
    for (int t = 0; t < 4; ++t) {
      const ushort_t* hr = xt + (t * 16 + m) * XSTRIDE;
      f16x8 af[4];
#pragma unroll
      for (int kb = 0; kb < 4; ++kb)
        af[kb] = *(const f16x8*)(hr + kb * 32 + quad * 8);
      f32x4 qa = {0.f, 0.f, 0.f, 0.f};
      f32x4 ka = {0.f, 0.f, 0.f, 0.f};
#pragma unroll
      for (int kb = 0; kb < 4; ++kb) qa = mfma_f16(af[kb], wqf[kb], qa);
#pragma unroll
      for (int kb = 0; kb < 4; ++kb) ka = mfma_f16(af[kb], wkf[kb], ka);
      float p0 = (qa[0] + bqv) * (ka[0] + bkv);
      float p1 = (qa[1] + bqv) * (ka[1] + bkv);
      float p2 = (qa[2] + bqv) * (ka[2] + bkv);
      float p3 = (qa[3] + bqv) * (ka[3] + bkv);
      float mx = fmaxf(fmaxf(p0, p1), fmaxf(p2, p3));
      mx = fmaxf(mx, __shfl_xor(mx, 16));
      mx = fmaxf(mx, __shfl_xor(mx, 32));
      float e0 = __expf(p0 - mx), e1 = __expf(p1 - mx);
      float e2 = __expf(p2 - mx), e3 = __expf(p3 - mx);
      float sm = (e0 + e1) + (e2 + e3);
      sm += __shfl_xor(sm, 16);
      sm += __shfl_xor(sm, 32);
      f32x4 va = {0.f, 0.f, 0.f, 0.f};
#pragma unroll
      for (int kb = 0; kb < 4; ++kb) va = mfma_f16(af[kb], wvf[kb], va);
      float r0 = e0 * va[0] + e1 * va[1] + e2 * va[2] + e3 * va[3];
      r0 += __shfl_xor(r0, 16);
      r0 += __shfl_xor(r0, 32);
      if (quad == 0) souts[(ch0 + m) * SOUTS + tbase + t] = r0 / sm + bvv;
    }
  }
}

// ---------------- K3 v7: 2-tile software pipeline ----------------
// 128 cols (8 positions) per block, grid 250xNB. Both tiles' global loads issue
// up front (10 dwordx4 in flight); tile B's data sits in registers through
// QKV-A (T14 issue-early/write-late) -> stage latency hidden under compute.
// LDS 39,424B -> 4 blocks/CU. (256,4): proven no-spill regime (VGPR~52+20).
__global__ __launch_bounds__(256, 4) void k_fused3(
    const ushort_t* __restrict__ hg, const float* __restrict__ x_row,
    const ushort_t* __restrict__ wb, const float* __restrict__ alpha,
    const float* __restrict__ beta, const float* __restrict__ bq,
    const float* __restrict__ bk, const float* __restrict__ bv,
    const float* __restrict__ g1p, float* __restrict__ out) {
  __shared__ ushort_t xtA[64 * XSTRIDE] __attribute__((aligned(16)));  // 17408 B
  __shared__ ushort_t xtB[64 * XSTRIDE] __attribute__((aligned(16)));  // 17408 B
  __shared__ float souts[128 * SOUTS];                                 // 4608 B
  const int b = blockIdx.y;
  const int tid = threadIdx.x;
  const int lane = tid & 63, w = tid >> 6;
  const int m = lane & 15, quad = lane >> 4;

  // hoist epilogue x_row loads
  const size_t oi = ((size_t)b * NC + tid) * NPOS + (size_t)blockIdx.x * 8;
  float4 xr0, xr1;
  if (tid < 128) {
    xr0 = *(const float4*)(x_row + oi);
    xr1 = *(const float4*)(x_row + oi + 4);
  }

  const uint4* srcA =
      (const uint4*)(hg + ((size_t)b * NK + (size_t)blockIdx.x * 128) * XSTRIDE);
  const uint4* srcB = srcA + 1088;
  uint4 vA[5], vB[5];
  tile_load(srcA, tid, vA);
  tile_load(srcB, tid, vB);  // in flight / in regs through QKV-A

  const float* ap = alpha + b * 128;
  const float* bp = beta + b * 128;
  tile_norm_store(vA, xtA, tid, ap, bp);
  const float g1 = g1p[0];
  __syncthreads();

  const ushort_t* wqb = wb + 16384;
  const ushort_t* wkb = wb + 32768;
  const ushort_t* wvb = wb + 49152;

  qkv_phase(xtA, souts, wqb, wkb, wvb, bq, bk, bv, w, m, quad, 0);

  tile_norm_store(vB, xtB, tid, ap, bp);
  __syncthreads();

  qkv_phase(xtB, souts, wqb, wkb, wvb, bq, bk, bv, w, m, quad, 4);
  __syncthreads();

  // ---- coalesced epilogue: out = x_row + g1 * souts (8 positions) ----
  if (tid < 128) {
    const float* sp = souts + tid * SOUTS;
    float4 o0, o1;
    o0.x = xr0.x + g1 * sp[0];
    o0.y = xr0.y + g1 * sp[1];
    o0.z = xr0.z + g1 * sp[2];
    o0.w = xr0.w + g1 * sp[3];
    o1.x = xr1.x + g1 * sp[4];
    o1.y = xr1.y + g1 * sp[5];
    o1.z = xr1.z + g1 * sp[6];
    o1.w = xr1.w + g1 * sp[7];
    *(float4*)(out + oi) = o0;
    *(float4*)(out + oi + 4) = o1;
  }
}

// =================== v1 fallback path (used only if workspace too small) ===================
__global__ __launch_bounds__(256, 4) void k_stats1(const float* __restrict__ x,
    const ushort_t* __restrict__ w0b, float* __restrict__ sumP,
    float* __restrict__ sqP) {
  __shared__ ushort_t xt[128 * XSTRIDE];
  __shared__ float ssum[128], ssq[128];
  const int b = blockIdx.y;
  const int tid = threadIdx.x;
  stage_xt128(x + (size_t)b * NC * NK + (size_t)blockIdx.x * 128, xt, tid);
  __syncthreads();
  const int lane = tid & 63, w = tid >> 6;
  const int m = lane & 15, quad = lane >> 4;

#pragma unroll 1
  for (int p = 0; p < 2; ++p) {
    const int ch0 = (w + p * 4) * 16;
    bf16x8 wf[4];
#pragma unroll
    for (int kb = 0; kb < 4; ++kb)
      wf[kb] = *(const bf16x8*)(w0b + (ch0 + m) * 128 + kb * 32 + quad * 8);
    float s = 0.f, q2 = 0.f;
#pragma unroll 2
    for (int t = 0; t < 8; ++t) {
      const ushort_t* xr = xt + (t * 16 + m) * XSTRIDE;
      f32x4 acc = {0.f, 0.f, 0.f, 0.f};
#pragma unroll
      for (int kb = 0; kb < 4; ++kb) {
        bf16x8 af = *(const bf16x8*)(xr + kb * 32 + quad * 8);
        acc = mfma_bf16(af, wf[kb], acc);
      }
      s += (acc[0] + acc[1]) + (acc[2] + acc[3]);
      q2 += (acc[0] * acc[0] + acc[1] * acc[1]) +
            (acc[2] * acc[2] + acc[3] * acc[3]);
    }
    s += __shfl_xor(s, 16);
    s += __shfl_xor(s, 32);
    q2 += __shfl_xor(q2, 16);
    q2 += __shfl_xor(q2, 32);
    if (quad == 0) {
      ssum[ch0 + m] = s;
      ssq[ch0 + m] = q2;
    }
  }
  __syncthreads();
  if (tid < 128) {
    const int bucket = blockIdx.x & 31;
    atomicAdd(&sumP[bucket * 1024 + b * 128 + tid], ssum[tid]);
    atomicAdd(&sqP[bucket * 1024 + b * 128 + tid], ssq[tid]);
  }
}

__global__ __launch_bounds__(256, 4) void k_fused1(const float* __restrict__ x,
    const float* __restrict__ x_row, const ushort_t* __restrict__ wb,
    const float* __restrict__ alpha, const float* __restrict__ beta,
    const float* __restrict__ bq, const float* __restrict__ bk,
    const float* __restrict__ bv, const float* __restrict__ g1p,
    float* __restrict__ out) {
  __shared__ ushort_t xt[64 * XSTRIDE];
  __shared__ ushort_t ht[64 * XSTRIDE];
  __shared__ float souts[128 * 5];
  const int b = blockIdx.y;
  const int tid = threadIdx.x;
  stage_xt64(x + (size_t)b * NC * NK + (size_t)blockIdx.x * 64, xt, tid);
  const float g1 = g1p[0];
  __syncthreads();
  const int lane = tid & 63, w = tid >> 6;
  const int m = lane & 15, quad = lane >> 4;
  const ushort_t* w0b = wb;
  const ushort_t* wqb = wb + 16384;
  const ushort_t* wkb = wb + 32768;
  const ushort_t* wvb = wb + 49152;

#pragma unroll 1
  for (int p = 0; p < 2; ++p) {
    const int ch0 = (w + p * 4) * 16;
    bf16x8 wf[4];
#pragma unroll
    for (int kb = 0; kb < 4; ++kb)
      wf[kb] = *(const bf16x8*)(w0b + (ch0 + m) * 128 + kb * 32 + quad * 8);
    const float4 av = *(const float4*)(alpha + b * 128 + ch0 + quad * 4);
    const float4 bev = *(const float4*)(beta + b * 128 + ch0 + quad * 4);
#pragma unroll
    for (int t = 0; t < 4; ++t) {
      const ushort_t* xr = xt + (t * 16 + m) * XSTRIDE;
      f32x4 acc = {0.f, 0.f, 0.f, 0.f};
#pragma unroll
      for (int kb = 0; kb < 4; ++kb) {
        bf16x8 bx = *(const bf16x8*)(xr + kb * 32 + quad * 8);
        acc = mfma_bf16(wf[kb], bx, acc);
      }
      float h0 = fmaxf(acc[0] * av.x + bev.x, 0.f);
      float h1 = fmaxf(acc[1] * av.y + bev.y, 0.f);
      float h2 = fmaxf(acc[2] * av.z + bev.z, 0.f);
      float h3 = fmaxf(acc[3] * av.w + bev.w, 0.f);
      uint2 pk;
      pk.x = (uint_t)f2bf(h0) | ((uint_t)f2bf(h1) << 16);
      pk.y = (uint_t)f2bf(h2) | ((uint_t)f2bf(h3) << 16);
      *(uint2*)(ht + (t * 16 + m) * XSTRIDE + ch0 + quad * 4) = pk;
    }
  }
  __syncthreads();

#pragma unroll 1
  for (int p = 0; p < 2; ++p) {
    const int ch0 = (w + p * 4) * 16;
    bf16x8 wqf[4], wkf[4], wvf[4];
#pragma unroll
    for (int kb = 0; kb < 4; ++kb) {
      wqf[kb] = *(const bf16x8*)(wqb + (ch0 + m) * 128 + kb * 32 + quad * 8);
      wkf[kb] = *(const bf16x8*)(wkb + (ch0 + m) * 128 + kb * 32 + quad * 8);
      wvf[kb] = *(const bf16x8*)(wvb + (ch0 + m) * 128 + kb * 32 + quad * 8);
    }
    const float bqv = bq[ch0 + m];
    const float bkv = bk[ch0 + m];
    const float bvv = bv[ch0 + m];
#pragma unroll 1
    for (int t = 0; t < 4; ++t) {
      const ushort_t* hr = ht + (t * 16 + m) * XSTRIDE;
      bf16x8 af[4];
#pragma unroll
      for (int kb = 0; kb < 4; ++kb)
        af[kb] = *(const bf16x8*)(hr + kb * 32 + quad * 8);
      f32x4 qa = {0.f, 0.f, 0.f, 0.f};
      f32x4 ka = {0.f, 0.f, 0.f, 0.f};
#pragma unroll
      for (int kb = 0; kb < 4; ++kb) qa = mfma_bf16(af[kb], wqf[kb], qa);
#pragma unroll
      for (int kb = 0; kb < 4; ++kb) ka = mfma_bf16(af[kb], wkf[kb], ka);
      float p0 = (qa[0] + bqv) * (ka[0] + bkv);
      float p1 = (qa[1] + bqv) * (ka[1] + bkv);
      float p2 = (qa[2] + bqv) * (ka[2] + bkv);
      float p3 = (qa[3] + bqv) * (ka[3] + bkv);
      float mx = fmaxf(fmaxf(p0, p1), fmaxf(p2, p3));
      mx = fmaxf(mx, __shfl_xor(mx, 16));
      mx = fmaxf(mx, __shfl_xor(mx, 32));
      float e0 = __expf(p0 - mx), e1 = __expf(p1 - mx);
      float e2 = __expf(p2 - mx), e3 = __expf(p3 - mx);
      float sm = (e0 + e1) + (e2 + e3);
      sm += __shfl_xor(sm, 16);
      sm += __shfl_xor(sm, 32);
      f32x4 va = {0.f, 0.f, 0.f, 0.f};
#pragma unroll
      for (int kb = 0; kb < 4; ++kb) va = mfma_bf16(af[kb], wvf[kb], va);
      float r0 = e0 * (va[0] + bvv) + e1 * (va[1] + bvv) +
                 e2 * (va[2] + bvv) + e3 * (va[3] + bvv);
      r0 += __shfl_xor(r0, 16);
      r0 += __shfl_xor(r0, 32);
      if (quad == 0) souts[(ch0 + m) * 5 + t] = r0 / sm;
    }
  }
  __syncthreads();

  if (tid < 128) {
    const int c = tid;
    const size_t oi = ((size_t)b * NC + c) * NPOS + blockIdx.x * 4;
    const float4 xr = *(const float4*)(x_row + oi);
    const float* sp = souts + c * 5;
    float4 o;
    o.x = xr.x + g1 * sp[0];
    o.y = xr.y + g1 * sp[1];
    o.z = xr.z + g1 * sp[2];
    o.w = xr.w + g1 * sp[3];
    *(float4*)(out + oi) = o;
  }
}

extern "C" void kernel_launch(void* const* d_in, const int* in_sizes, int n_in,
                              void* d_out, int out_size, void* d_ws, size_t ws_size,
                              hipStream_t stream) {
  (void)in_sizes; (void)n_in; (void)out_size;
  const float* x_row   = (const float*)d_in[0];
  const float* x_local = (const float*)d_in[1];
  const float* w0   = (const float*)d_in[2];
  const float* bn_g = (const float*)d_in[4];
  const float* bn_b = (const float*)d_in[5];
  const float* wq   = (const float*)d_in[6];
  const float* bq   = (const float*)d_in[7];
  const float* wk   = (const float*)d_in[8];
  const float* bk   = (const float*)d_in[9];
  const float* wv   = (const float*)d_in[10];
  const float* bv   = (const float*)d_in[11];
  const float* gamma1 = (const float*)d_in[12];
  float* out = (float*)d_out;
  float* ws = (float*)d_ws;
  ushort_t* wb = (ushort_t*)((char*)d_ws + WSB_WEIGHTS);
  ushort_t* hg = (ushort_t*)((char*)d_ws + WSB_H);

  (void)hipMemsetAsync(ws, 0, 65536 * sizeof(float), stream);  // bucketed accumulators

  if (ws_size >= WS_NEEDED) {
    k_prep<1><<<256, 256, 0, stream>>>(w0, wq, wk, wv, wb);
    k_stats2<<<dim3(500, NB), 256, 0, stream>>>(x_local, wb, ws + WSF_SUMP,
                                                ws + WSF_SQP, hg);
    k_fold<<<1, 128, 0, stream>>>(ws, bn_g, bn_b, ws + WSF_ALPHA, ws + WSF_BETA);
    k_fused3<<<dim3(250, NB), 256, 0, stream>>>(hg, x_row, wb, ws + WSF_ALPHA,
                                                ws + WSF_BETA, bq, bk, bv, gamma1,
                                                out);
  } else {
    // workspace too small for the h buffer: previous verified pipeline
    k_prep<0><<<256, 256, 0, stream>>>(w0, wq, wk, wv, wb);
    k_stats1<<<dim3(250, NB), 256, 0, stream>>>(x_local, wb, ws + WSF_SUMP,
                                                ws + WSF_SQP);
    k_fold<<<1, 128, 0, stream>>>(ws, bn_g, bn_b, ws + WSF_ALPHA, ws + WSF_BETA);
    k_fused1<<<dim3(500, NB), 256, 0, stream>>>(x_local, x_row, wb, ws + WSF_ALPHA,
                                                ws + WSF_BETA, bq, bk, bv, gamma1,
                                                out);
  }
}

// Round 9
// 316.399 us; speedup vs baseline: 1.2151x; 1.0087x over previous
//
#include <hip/hip_runtime.h>
#include <math.h>

#define NB 8
#define NC 128
#define NPOS 2000
#define NK 32000
#define IN_EPS 1e-3f
#define BN_EPS 1e-5f

typedef short bf16x8 __attribute__((ext_vector_type(8)));
typedef _Float16 f16x8 __attribute__((ext_vector_type(8)));
typedef float f32x4 __attribute__((ext_vector_type(4)));
typedef unsigned short ushort_t;
typedef unsigned int uint_t;

// LDS row stride in ushorts (128 payload + 8 pad; keeps 16B alignment, 272B rows)
#define XSTRIDE 136

// ---- workspace layout ----
#define WSF_SUMP  0
#define WSF_SQP   32768
#define WSF_ALPHA 65536
#define WSF_BETA  66560
#define WSB_WEIGHTS 270336
#define WSB_H     401408
#define WS_NEEDED ((size_t)WSB_H + (size_t)NB * NK * XSTRIDE * 2)

__device__ __forceinline__ f32x4 mfma_bf16(bf16x8 a, bf16x8 b, f32x4 c) {
  return __builtin_amdgcn_mfma_f32_16x16x32_bf16(a, b, c, 0, 0, 0);
}
__device__ __forceinline__ f32x4 mfma_f16(f16x8 a, f16x8 b, f32x4 c) {
  return __builtin_amdgcn_mfma_f32_16x16x32_f16(a, b, c, 0, 0, 0);
}

__device__ __forceinline__ ushort_t f2bf(float f) {
  unsigned u = __float_as_uint(f);
  return (ushort_t)((u + 0x7FFFu + ((u >> 16) & 1u)) >> 16);
}
__device__ __forceinline__ ushort_t f2h(float f) {
  union { _Float16 h; ushort_t u; } cv;
  cv.h = (_Float16)f;
  return cv.u;
}
__device__ __forceinline__ float h2f(ushort_t u) {
  union { _Float16 h; ushort_t u; } cv;
  cv.u = u;
  return (float)cv.h;
}
__device__ __forceinline__ uint_t pk2h(float a, float b) {
  auto h = __builtin_amdgcn_cvt_pkrtz(a, b);
  return __builtin_bit_cast(uint_t, h);
}

// ---------------- K0: cast weights ----------------
template <int ALL_F16>
__global__ __launch_bounds__(256) void k_prep(const float* __restrict__ w0,
    const float* __restrict__ wq, const float* __restrict__ wk,
    const float* __restrict__ wv, ushort_t* __restrict__ wb) {
  int idx = blockIdx.x * 256 + threadIdx.x;  // 0..65535
  int m = idx >> 14;
  int e = idx & 16383;
  const float* src = (m == 0) ? w0 : (m == 1) ? wq : (m == 2) ? wk : wv;
  float v = src[e];
  wb[m * 16384 + e] = ALL_F16 ? f2h(v) : f2bf(v);
}

// ---- staging (v1 fallback): Xt[col][cin] bf16, 128 columns ----
__device__ __forceinline__ void stage_xt128(const float* __restrict__ xb,
                                            ushort_t* __restrict__ xt, int tid) {
  const int col = tid & 127;
  const int hi = tid >> 7;
  const float* p = xb + col;
#pragma unroll
  for (int i = 0; i < 8; ++i) {
    const int c0 = hi * 64 + i * 8;
    ushort_t u[8] __attribute__((aligned(16)));
#pragma unroll
    for (int j = 0; j < 8; ++j) u[j] = f2bf(p[(size_t)(c0 + j) * NK]);
    *(uint4*)(xt + col * XSTRIDE + c0) = *(const uint4*)u;
  }
}

// ---- staging (v1 fallback): 64 columns, bf16 ----
__device__ __forceinline__ void stage_xt64(const float* __restrict__ xb,
                                           ushort_t* __restrict__ xt, int tid) {
  const int col = tid & 63;
  const int hi = tid >> 6;
  const float* p = xb + col;
#pragma unroll
  for (int i = 0; i < 4; ++i) {
    const int c0 = hi * 32 + i * 8;
    ushort_t u[8] __attribute__((aligned(16)));
#pragma unroll
    for (int j = 0; j < 8; ++j) u[j] = f2bf(p[(size_t)(c0 + j) * NK]);
    *(uint4*)(xt + col * XSTRIDE + c0) = *(const uint4*)u;
  }
}

// ---- staging v4: 64 columns, fp16 via v_cvt_pkrtz ----
__device__ __forceinline__ void stage_xt64_f16(const float* __restrict__ xb,
                                               ushort_t* __restrict__ xt, int tid) {
  const int col = tid & 63;
  const int hi = tid >> 6;
  const float* p = xb + col;
#pragma unroll
  for (int r = 0; r < 2; ++r) {
    const int c0 = hi * 32 + r * 16;
    float v[16];
#pragma unroll
    for (int j = 0; j < 16; ++j) v[j] = p[(size_t)(c0 + j) * NK];
    uint_t u[8] __attribute__((aligned(16)));
#pragma unroll
    for (int j = 0; j < 8; ++j) u[j] = pk2h(v[2 * j], v[2 * j + 1]);
    *(uint4*)(xt + col * XSTRIDE + c0) = *(const uint4*)u;
    *(uint4*)(xt + col * XSTRIDE + c0 + 8) = *(const uint4*)(u + 4);
  }
}

// ---------------- K1 v4: conv (f16) + stats + materialize h ----------------
__global__ __launch_bounds__(256, 6) void k_stats2(const float* __restrict__ x,
    const ushort_t* __restrict__ w0b, float* __restrict__ sumP,
    float* __restrict__ sqP, ushort_t* __restrict__ hg) {
  __shared__ ushort_t xt[64 * XSTRIDE] __attribute__((aligned(16)));
  __shared__ float ssum[128], ssq[128];
  const int b = blockIdx.y;
  const int tid = threadIdx.x;
  stage_xt64_f16(x + (size_t)b * NC * NK + (size_t)blockIdx.x * 64, xt, tid);
  __syncthreads();
  const int lane = tid & 63, w = tid >> 6;
  const int m = lane & 15, quad = lane >> 4;

  uint2 hreg[8];  // [p*4+t], statically indexed

#pragma unroll
  for (int p = 0; p < 2; ++p) {
    const int ch0 = (w + p * 4) * 16;
    f16x8 wf[4];
#pragma unroll
    for (int kb = 0; kb < 4; ++kb)
      wf[kb] = *(const f16x8*)(w0b + (ch0 + m) * 128 + kb * 32 + quad * 8);
    float s0 = 0.f, s1 = 0.f, s2 = 0.f, s3 = 0.f;
    float q0 = 0.f, q1 = 0.f, q2 = 0.f, q3 = 0.f;
#pragma unroll
    for (int t = 0; t < 4; ++t) {
      const ushort_t* xr = xt + (t * 16 + m) * XSTRIDE;
      f32x4 acc = {0.f, 0.f, 0.f, 0.f};
#pragma unroll
      for (int kb = 0; kb < 4; ++kb) {
        f16x8 bx = *(const f16x8*)(xr + kb * 32 + quad * 8);
        acc = mfma_f16(wf[kb], bx, acc);
      }
      const ushort_t u0 = f2h(acc[0]), u1 = f2h(acc[1]);
      const ushort_t u2 = f2h(acc[2]), u3 = f2h(acc[3]);
      uint2 pk;
      pk.x = (uint_t)u0 | ((uint_t)u1 << 16);
      pk.y = (uint_t)u2 | ((uint_t)u3 << 16);
      hreg[p * 4 + t] = pk;
      const float r0 = h2f(u0), r1 = h2f(u1), r2 = h2f(u2), r3 = h2f(u3);
      s0 += r0; s1 += r1; s2 += r2; s3 += r3;
      q0 = fmaf(r0, r0, q0); q1 = fmaf(r1, r1, q1);
      q2 = fmaf(r2, r2, q2); q3 = fmaf(r3, r3, q3);
    }
#pragma unroll
    for (int d = 1; d < 16; d <<= 1) {
      s0 += __shfl_xor(s0, d); s1 += __shfl_xor(s1, d);
      s2 += __shfl_xor(s2, d); s3 += __shfl_xor(s3, d);
      q0 += __shfl_xor(q0, d); q1 += __shfl_xor(q1, d);
      q2 += __shfl_xor(q2, d); q3 += __shfl_xor(q3, d);
    }
    if (m == 0) {
      ssum[ch0 + quad * 4 + 0] = s0; ssum[ch0 + quad * 4 + 1] = s1;
      ssum[ch0 + quad * 4 + 2] = s2; ssum[ch0 + quad * 4 + 3] = s3;
      ssq[ch0 + quad * 4 + 0] = q0; ssq[ch0 + quad * 4 + 1] = q1;
      ssq[ch0 + quad * 4 + 2] = q2; ssq[ch0 + quad * 4 + 3] = q3;
    }
  }
  __syncthreads();

#pragma unroll
  for (int p = 0; p < 2; ++p) {
    const int ch0 = (w + p * 4) * 16;
#pragma unroll
    for (int t = 0; t < 4; ++t)
      *(uint2*)(xt + (t * 16 + m) * XSTRIDE + ch0 + quad * 4) = hreg[p * 4 + t];
  }
  __syncthreads();

  {
    const uint4* src = (const uint4*)xt;
    uint4* dst =
        (uint4*)(hg + ((size_t)b * NK + (size_t)blockIdx.x * 64) * XSTRIDE);
#pragma unroll
    for (int i = 0; i < 4; ++i) dst[i * 256 + tid] = src[i * 256 + tid];
    if (tid < 64) dst[1024 + tid] = src[1024 + tid];
  }

  if (tid < 128) {
    const int bucket = blockIdx.x & 31;
    atomicAdd(&sumP[bucket * 1024 + b * 128 + tid], ssum[tid]);
    atomicAdd(&sqP[bucket * 1024 + b * 128 + tid], ssq[tid]);
  }
}

// ---------------- K2: fold IN+BN into per-(b,c) alpha/beta ----------------
__global__ void k_fold(const float* __restrict__ ws_in, const float* __restrict__ bn_g,
                       const float* __restrict__ bn_b, float* __restrict__ alpha,
                       float* __restrict__ beta) {
  int c = threadIdx.x;  // 128 threads
  const float* sumP = ws_in + WSF_SUMP;
  const float* sqP = ws_in + WSF_SQP;
  float var[NB], muv[NB];
  float bvar = 0.f;
#pragma unroll 1
  for (int b = 0; b < NB; ++b) {
    float s = 0.f, q = 0.f;
#pragma unroll
    for (int k = 0; k < 32; ++k) {
      s += sumP[k * 1024 + b * 128 + c];
      q += sqP[k * 1024 + b * 128 + c];
    }
    float mu = s * (1.f / NK);
    float v = q * (1.f / NK) - mu * mu;
    muv[b] = mu;
    var[b] = v;
    bvar += v / (v + IN_EPS);
  }
  bvar *= 0.125f;
  float s2 = rsqrtf(bvar + BN_EPS);
  float g = bn_g[c], bb = bn_b[c];
#pragma unroll
  for (int b = 0; b < NB; ++b) {
    float a = rsqrtf(var[b] + IN_EPS) * s2 * g;
    alpha[b * 128 + c] = a;
    beta[b * 128 + c] = bb - muv[b] * a;
  }
}

__device__ __forceinline__ uint_t norm2(uint_t hv, float a0, float a1, float c0,
                                        float c1) {
  float lo = h2f((ushort_t)(hv & 0xffffu));
  float hi = h2f((ushort_t)(hv >> 16));
  return pk2h(fmaxf(fmaf(lo, a0, c0), 0.f), fmaxf(fmaf(hi, a1, c1), 0.f));
}

// ---------------- K3 v8: single tile, norm fused in staging, t-loop unroll 2 ----------------
// (256,4): the only proven no-spill regime. 2-tile pipeline (r8) was null ->
// cost is per-wave chain latency, not staging; unroll 2 interleaves two
// independent per-position chains (MFMA-accum -> shfl-max -> exp -> shfl-sum
// -> MFMA -> shfl) to fill pipes at fixed occupancy. Reg est ~120 < 128.
__global__ __launch_bounds__(256, 4) void k_fused2(
    const ushort_t* __restrict__ hg, const float* __restrict__ x_row,
    const ushort_t* __restrict__ wb, const float* __restrict__ alpha,
    const float* __restrict__ beta, const float* __restrict__ bq,
    const float* __restrict__ bk, const float* __restrict__ bv,
    const float* __restrict__ g1p, float* __restrict__ out) {
  __shared__ ushort_t xt[64 * XSTRIDE] __attribute__((aligned(16)));  // 17408 B
  __shared__ float souts[128 * 5];                                    // 2560 B
  const int b = blockIdx.y;
  const int tid = threadIdx.x;
  const int lane = tid & 63, w = tid >> 6;

  // hoist epilogue x_row load
  const size_t oi = ((size_t)b * NC + tid) * NPOS + blockIdx.x * 4;
  float4 xr_early;
  if (tid < 128) xr_early = *(const float4*)(x_row + oi);

  // stage + fused norm: 1088 uint4 chunks. Row = j/17; chunk c=j%17 covers
  // channels c*8..c*8+7 (c==16 is the 16B pad -> raw copy).
  {
    const uint4* src =
        (const uint4*)(hg + ((size_t)b * NK + (size_t)blockIdx.x * 64) * XSTRIDE);
    uint4* dst = (uint4*)xt;
    const float* ap = alpha + b * 128;
    const float* bp = beta + b * 128;
#pragma unroll
    for (int i = 0; i < 5; ++i) {
      if (i < 4 || tid < 64) {
        const int j = i * 256 + tid;
        uint4 v = src[j];
        const int c = j % 17;
        if (c < 16) {
          const int ch = c * 8;
          const float4 a0 = *(const float4*)(ap + ch);
          const float4 a1 = *(const float4*)(ap + ch + 4);
          const float4 c0 = *(const float4*)(bp + ch);
          const float4 c1 = *(const float4*)(bp + ch + 4);
          v.x = norm2(v.x, a0.x, a0.y, c0.x, c0.y);
          v.y = norm2(v.y, a0.z, a0.w, c0.z, c0.w);
          v.z = norm2(v.z, a1.x, a1.y, c1.x, c1.y);
          v.w = norm2(v.w, a1.z, a1.w, c1.z, c1.w);
        }
        dst[j] = v;
      }
    }
  }
  const float g1 = g1p[0];
  __syncthreads();

  // ---- QKV phase (fp16), t-loop unrolled 2x for ILP ----
  const int m = lane & 15, quad = lane >> 4;
  const ushort_t* wqb = wb + 16384;
  const ushort_t* wkb = wb + 32768;
  const ushort_t* wvb = wb + 49152;
#pragma unroll 1
  for (int p = 0; p < 2; ++p) {
    const int ch0 = (w + p * 4) * 16;
    f16x8 wqf[4], wkf[4], wvf[4];
#pragma unroll
    for (int kb = 0; kb < 4; ++kb) {
      wqf[kb] = *(const f16x8*)(wqb + (ch0 + m) * 128 + kb * 32 + quad * 8);
      wkf[kb] = *(const f16x8*)(wkb + (ch0 + m) * 128 + kb * 32 + quad * 8);
      wvf[kb] = *(const f16x8*)(wvb + (ch0 + m) * 128 + kb * 32 + quad * 8);
    }
    const float bqv = bq[ch0 + m];
    const float bkv = bk[ch0 + m];
    const float bvv = bv[ch0 + m];
#pragma unroll 1
    for (int tt = 0; tt < 2; ++tt) {
#pragma unroll
      for (int u = 0; u < 2; ++u) {  // two independent chains, interleaved
        const int t = tt * 2 + u;
        const ushort_t* hr = xt + (t * 16 + m) * XSTRIDE;
        f16x8 af[4];
#pragma unroll
        for (int kb = 0; kb < 4; ++kb)
          af[kb] = *(const f16x8*)(hr + kb * 32 + quad * 8);
        f32x4 qa = {0.f, 0.f, 0.f, 0.f};
        f32x4 ka = {0.f, 0.f, 0.f, 0.f};
#pragma unroll
        for (int kb = 0; kb < 4; ++kb) qa = mfma_f16(af[kb], wqf[kb], qa);
#pragma unroll
        for (int kb = 0; kb < 4; ++kb) ka = mfma_f16(af[kb], wkf[kb], ka);
        float p0 = (qa[0] + bqv) * (ka[0] + bkv);
        float p1 = (qa[1] + bqv) * (ka[1] + bkv);
        float p2 = (qa[2] + bqv) * (ka[2] + bkv);
        float p3 = (qa[3] + bqv) * (ka[3] + bkv);
        float mx = fmaxf(fmaxf(p0, p1), fmaxf(p2, p3));
        mx = fmaxf(mx, __shfl_xor(mx, 16));
        mx = fmaxf(mx, __shfl_xor(mx, 32));
        float e0 = __expf(p0 - mx), e1 = __expf(p1 - mx);
        float e2 = __expf(p2 - mx), e3 = __expf(p3 - mx);
        float sm = (e0 + e1) + (e2 + e3);
        sm += __shfl_xor(sm, 16);
        sm += __shfl_xor(sm, 32);
        f32x4 va = {0.f, 0.f, 0.f, 0.f};
#pragma unroll
        for (int kb = 0; kb < 4; ++kb) va = mfma_f16(af[kb], wvf[kb], va);
        float r0 = e0 * va[0] + e1 * va[1] + e2 * va[2] + e3 * va[3];
        r0 += __shfl_xor(r0, 16);
        r0 += __shfl_xor(r0, 32);
        if (quad == 0) souts[(ch0 + m) * 5 + t] = r0 / sm + bvv;
      }
    }
  }
  __syncthreads();

  // ---- coalesced epilogue: out = x_row + g1 * souts ----
  if (tid < 128) {
    const float* sp = souts + tid * 5;
    float4 o;
    o.x = xr_early.x + g1 * sp[0];
    o.y = xr_early.y + g1 * sp[1];
    o.z = xr_early.z + g1 * sp[2];
    o.w = xr_early.w + g1 * sp[3];
    *(float4*)(out + oi) = o;
  }
}

// =================== v1 fallback path (used only if workspace too small) ===================
__global__ __launch_bounds__(256, 4) void k_stats1(const float* __restrict__ x,
    const ushort_t* __restrict__ w0b, float* __restrict__ sumP,
    float* __restrict__ sqP) {
  __shared__ ushort_t xt[128 * XSTRIDE];
  __shared__ float ssum[128], ssq[128];
  const int b = blockIdx.y;
  const int tid = threadIdx.x;
  stage_xt128(x + (size_t)b * NC * NK + (size_t)blockIdx.x * 128, xt, tid);
  __syncthreads();
  const int lane = tid & 63, w = tid >> 6;
  const int m = lane & 15, quad = lane >> 4;

#pragma unroll 1
  for (int p = 0; p < 2; ++p) {
    const int ch0 = (w + p * 4) * 16;
    bf16x8 wf[4];
#pragma unroll
    for (int kb = 0; kb < 4; ++kb)
      wf[kb] = *(const bf16x8*)(w0b + (ch0 + m) * 128 + kb * 32 + quad * 8);
    float s = 0.f, q2 = 0.f;
#pragma unroll 2
    for (int t = 0; t < 8; ++t) {
      const ushort_t* xr = xt + (t * 16 + m) * XSTRIDE;
      f32x4 acc = {0.f, 0.f, 0.f, 0.f};
#pragma unroll
      for (int kb = 0; kb < 4; ++kb) {
        bf16x8 af = *(const bf16x8*)(xr + kb * 32 + quad * 8);
        acc = mfma_bf16(af, wf[kb], acc);
      }
      s += (acc[0] + acc[1]) + (acc[2] + acc[3]);
      q2 += (acc[0] * acc[0] + acc[1] * acc[1]) +
            (acc[2] * acc[2] + acc[3] * acc[3]);
    }
    s += __shfl_xor(s, 16);
    s += __shfl_xor(s, 32);
    q2 += __shfl_xor(q2, 16);
    q2 += __shfl_xor(q2, 32);
    if (quad == 0) {
      ssum[ch0 + m] = s;
      ssq[ch0 + m] = q2;
    }
  }
  __syncthreads();
  if (tid < 128) {
    const int bucket = blockIdx.x & 31;
    atomicAdd(&sumP[bucket * 1024 + b * 128 + tid], ssum[tid]);
    atomicAdd(&sqP[bucket * 1024 + b * 128 + tid], ssq[tid]);
  }
}

__global__ __launch_bounds__(256, 4) void k_fused1(const float* __restrict__ x,
    const float* __restrict__ x_row, const ushort_t* __restrict__ wb,
    const float* __restrict__ alpha, const float* __restrict__ beta,
    const float* __restrict__ bq, const float* __restrict__ bk,
    const float* __restrict__ bv, const float* __restrict__ g1p,
    float* __restrict__ out) {
  __shared__ ushort_t xt[64 * XSTRIDE];
  __shared__ ushort_t ht[64 * XSTRIDE];
  __shared__ float souts[128 * 5];
  const int b = blockIdx.y;
  const int tid = threadIdx.x;
  stage_xt64(x + (size_t)b * NC * NK + (size_t)blockIdx.x * 64, xt, tid);
  const float g1 = g1p[0];
  __syncthreads();
  const int lane = tid & 63, w = tid >> 6;
  const int m = lane & 15, quad = lane >> 4;
  const ushort_t* w0b = wb;
  const ushort_t* wqb = wb + 16384;
  const ushort_t* wkb = wb + 32768;
  const ushort_t* wvb = wb + 49152;

#pragma unroll 1
  for (int p = 0; p < 2; ++p) {
    const int ch0 = (w + p * 4) * 16;
    bf16x8 wf[4];
#pragma unroll
    for (int kb = 0; kb < 4; ++kb)
      wf[kb] = *(const bf16x8*)(w0b + (ch0 + m) * 128 + kb * 32 + quad * 8);
    const float4 av = *(const float4*)(alpha + b * 128 + ch0 + quad * 4);
    const float4 bev = *(const float4*)(beta + b * 128 + ch0 + quad * 4);
#pragma unroll
    for (int t = 0; t < 4; ++t) {
      const ushort_t* xr = xt + (t * 16 + m) * XSTRIDE;
      f32x4 acc = {0.f, 0.f, 0.f, 0.f};
#pragma unroll
      for (int kb = 0; kb < 4; ++kb) {
        bf16x8 bx = *(const bf16x8*)(xr + kb * 32 + quad * 8);
        acc = mfma_bf16(wf[kb], bx, acc);
      }
      float h0 = fmaxf(acc[0] * av.x + bev.x, 0.f);
      float h1 = fmaxf(acc[1] * av.y + bev.y, 0.f);
      float h2 = fmaxf(acc[2] * av.z + bev.z, 0.f);
      float h3 = fmaxf(acc[3] * av.w + bev.w, 0.f);
      uint2 pk;
      pk.x = (uint_t)f2bf(h0) | ((uint_t)f2bf(h1) << 16);
      pk.y = (uint_t)f2bf(h2) | ((uint_t)f2bf(h3) << 16);
      *(uint2*)(ht + (t * 16 + m) * XSTRIDE + ch0 + quad * 4) = pk;
    }
  }
  __syncthreads();

#pragma unroll 1
  for (int p = 0; p < 2; ++p) {
    const int ch0 = (w + p * 4) * 16;
    bf16x8 wqf[4], wkf[4], wvf[4];
#pragma unroll
    for (int kb = 0; kb < 4; ++kb) {
      wqf[kb] = *(const bf16x8*)(wqb + (ch0 + m) * 128 + kb * 32 + quad * 8);
      wkf[kb] = *(const bf16x8*)(wkb + (ch0 + m) * 128 + kb * 32 + quad * 8);
      wvf[kb] = *(const bf16x8*)(wvb + (ch0 + m) * 128 + kb * 32 + quad * 8);
    }
    const float bqv = bq[ch0 + m];
    const float bkv = bk[ch0 + m];
    const float bvv = bv[ch0 + m];
#pragma unroll 1
    for (int t = 0; t < 4; ++t) {
      const ushort_t* hr = ht + (t * 16 + m) * XSTRIDE;
      bf16x8 af[4];
#pragma unroll
      for (int kb = 0; kb < 4; ++kb)
        af[kb] = *(const bf16x8*)(hr + kb * 32 + quad * 8);
      f32x4 qa = {0.f, 0.f, 0.f, 0.f};
      f32x4 ka = {0.f, 0.f, 0.f, 0.f};
#pragma unroll
      for (int kb = 0; kb < 4; ++kb) qa = mfma_bf16(af[kb], wqf[kb], qa);
#pragma unroll
      for (int kb = 0; kb < 4; ++kb) ka = mfma_bf16(af[kb], wkf[kb], ka);
      float p0 = (qa[0] + bqv) * (ka[0] + bkv);
      float p1 = (qa[1] + bqv) * (ka[1] + bkv);
      float p2 = (qa[2] + bqv) * (ka[2] + bkv);
      float p3 = (qa[3] + bqv) * (ka[3] + bkv);
      float mx = fmaxf(fmaxf(p0, p1), fmaxf(p2, p3));
      mx = fmaxf(mx, __shfl_xor(mx, 16));
      mx = fmaxf(mx, __shfl_xor(mx, 32));
      float e0 = __expf(p0 - mx), e1 = __expf(p1 - mx);
      float e2 = __expf(p2 - mx), e3 = __expf(p3 - mx);
      float sm = (e0 + e1) + (e2 + e3);
      sm += __shfl_xor(sm, 16);
      sm += __shfl_xor(sm, 32);
      f32x4 va = {0.f, 0.f, 0.f, 0.f};
#pragma unroll
      for (int kb = 0; kb < 4; ++kb) va = mfma_bf16(af[kb], wvf[kb], va);
      float r0 = e0 * (va[0] + bvv) + e1 * (va[1] + bvv) +
                 e2 * (va[2] + bvv) + e3 * (va[3] + bvv);
      r0 += __shfl_xor(r0, 16);
      r0 += __shfl_xor(r0, 32);
      if (quad == 0) souts[(ch0 + m) * 5 + t] = r0 / sm;
    }
  }
  __syncthreads();

  if (tid < 128) {
    const int c = tid;
    const size_t oi = ((size_t)b * NC + c) * NPOS + blockIdx.x * 4;
    const float4 xr = *(const float4*)(x_row + oi);
    const float* sp = souts + c * 5;
    float4 o;
    o.x = xr.x + g1 * sp[0];
    o.y = xr.y + g1 * sp[1];
    o.z = xr.z + g1 * sp[2];
    o.w = xr.w + g1 * sp[3];
    *(float4*)(out + oi) = o;
  }
}

extern "C" void kernel_launch(void* const* d_in, const int* in_sizes, int n_in,
                              void* d_out, int out_size, void* d_ws, size_t ws_size,
                              hipStream_t stream) {
  (void)in_sizes; (void)n_in; (void)out_size;
  const float* x_row   = (const float*)d_in[0];
  const float* x_local = (const float*)d_in[1];
  const float* w0   = (const float*)d_in[2];
  const float* bn_g = (const float*)d_in[4];
  const float* bn_b = (const float*)d_in[5];
  const float* wq   = (const float*)d_in[6];
  const float* bq   = (const float*)d_in[7];
  const float* wk   = (const float*)d_in[8];
  const float* bk   = (const float*)d_in[9];
  const float* wv   = (const float*)d_in[10];
  const float* bv   = (const float*)d_in[11];
  const float* gamma1 = (const float*)d_in[12];
  float* out = (float*)d_out;
  float* ws = (float*)d_ws;
  ushort_t* wb = (ushort_t*)((char*)d_ws + WSB_WEIGHTS);
  ushort_t* hg = (ushort_t*)((char*)d_ws + WSB_H);

  (void)hipMemsetAsync(ws, 0, 65536 * sizeof(float), stream);  // bucketed accumulators

  if (ws_size >= WS_NEEDED) {
    k_prep<1><<<256, 256, 0, stream>>>(w0, wq, wk, wv, wb);
    k_stats2<<<dim3(500, NB), 256, 0, stream>>>(x_local, wb, ws + WSF_SUMP,
                                                ws + WSF_SQP, hg);
    k_fold<<<1, 128, 0, stream>>>(ws, bn_g, bn_b, ws + WSF_ALPHA, ws + WSF_BETA);
    k_fused2<<<dim3(500, NB), 256, 0, stream>>>(hg, x_row, wb, ws + WSF_ALPHA,
                                                ws + WSF_BETA, bq, bk, bv, gamma1,
                                                out);
  } else {
    // workspace too small for the h buffer: previous verified pipeline
    k_prep<0><<<256, 256, 0, stream>>>(w0, wq, wk, wv, wb);
    k_stats1<<<dim3(250, NB), 256, 0, stream>>>(x_local, wb, ws + WSF_SUMP,
                                                ws + WSF_SQP);
    k_fold<<<1, 128, 0, stream>>>(ws, bn_g, bn_b, ws + WSF_ALPHA, ws + WSF_BETA);
    k_fused1<<<dim3(500, NB), 256, 0, stream>>>(x_local, x_row, wb, ws + WSF_ALPHA,
                                                ws + WSF_BETA, bq, bk, bv, gamma1,
                                                out);
  }
}